// Round 9
// baseline (2158.206 us; speedup 1.0000x reference)
//
#include <hip/hip_runtime.h>
#include <math.h>

#define HID 128
#define NB 32     // nodes per block
#define SBST 136  // padded bf16 row stride for s_bf (16B-aligned, 2-way banks)
#define CSH 9     // coarse bucket = dst >> CSH (512 nodes/bucket)
#define MCH 8192  // edges per multisplit block
#define GOFF (32 * SBST)   // h0_k epilogue: g-staging offset inside LDS
#define CAP 1024  // per-block staged edge capacity (mean 512, +22 sigma safe)

typedef unsigned int uint32;
typedef unsigned short ushort_t;
typedef __attribute__((ext_vector_type(8))) short bf16x8;
typedef __attribute__((ext_vector_type(4))) float f32x4;

__device__ __forceinline__ unsigned short f2bf(float f) {
    unsigned u = __float_as_uint(f);
    u += 0x7FFF + ((u >> 16) & 1);          // round-to-nearest-even
    return (unsigned short)(u >> 16);
}
__device__ __forceinline__ float bf_lo(uint32 u) { return __uint_as_float(u << 16); }
__device__ __forceinline__ float bf_hi(uint32 u) { return __uint_as_float(u & 0xFFFF0000u); }

// ---------- CSR build ----------
__global__ void degree_k(const int* __restrict__ col, int* __restrict__ counts, int E) {
    int e = blockIdx.x * 256 + threadIdx.x;
    if (e < E) atomicAdd(&counts[col[e]], 1);
}

// scan1 also emits dinv = rsqrt(deg+1)
__global__ void scan1_k(const int* __restrict__ counts, int* __restrict__ row_ptr,
                        int* __restrict__ blocksums, float* __restrict__ dinv, int N) {
    __shared__ int tmp[256];
    int t = threadIdx.x;
    int i = blockIdx.x * 256 + t;
    int v = (i < N) ? counts[i] : 0;
    if (i < N) dinv[i] = rsqrtf((float)v + 1.0f);
    tmp[t] = v;
    __syncthreads();
    for (int off = 1; off < 256; off <<= 1) {
        int x = (t >= off) ? tmp[t - off] : 0;
        __syncthreads();
        tmp[t] += x;
        __syncthreads();
    }
    if (i < N) row_ptr[i] = tmp[t] - v;
    if (t == 255) blocksums[blockIdx.x] = tmp[t];
}

__global__ void scan2_k(const int* __restrict__ blocksums, int* __restrict__ blockoffs, int nb) {
    __shared__ int tmp[512];
    int t = threadIdx.x;
    int v = (t < nb) ? blocksums[t] : 0;
    tmp[t] = v;
    __syncthreads();
    for (int off = 1; off < 512; off <<= 1) {
        int x = (t >= off) ? tmp[t - off] : 0;
        __syncthreads();
        tmp[t] += x;
        __syncthreads();
    }
    if (t < nb) blockoffs[t] = tmp[t] - v;
}

// scan3 also initializes per-node cursor AND per-coarse-bucket cursor
__global__ void scan3_k(int* __restrict__ row_ptr, int* __restrict__ cursor,
                        int* __restrict__ ccursor,
                        const int* __restrict__ blockoffs, int N, int E) {
    int i = blockIdx.x * 256 + threadIdx.x;
    if (i < N) {
        int v = row_ptr[i] + blockoffs[blockIdx.x];
        row_ptr[i] = v;
        cursor[i] = v;
        if ((i & ((1 << CSH) - 1)) == 0) ccursor[i >> CSH] = v;
    }
    if (i == 0) row_ptr[N] = E;
}

// ---- scatter pass 1: block-aggregated multisplit into coarse buckets.
__global__ __launch_bounds__(256) void multisplit_k(const int* __restrict__ row,
                                                    const int* __restrict__ col,
                                                    int* __restrict__ ccursor,
                                                    int2* __restrict__ ebuf,
                                                    int E, int NCO) {
    __shared__ int lcnt[256];
    __shared__ int gbase[256];
    __shared__ int lpos[256];
    int t = threadIdx.x;
    int e0 = blockIdx.x * MCH;
    lcnt[t] = 0;
    lpos[t] = 0;
    __syncthreads();
    for (int i = t; i < MCH; i += 256) {
        int e = e0 + i;
        if (e < E) atomicAdd(&lcnt[col[e] >> CSH], 1);
    }
    __syncthreads();
    if (t < NCO && lcnt[t] > 0) gbase[t] = atomicAdd(&ccursor[t], lcnt[t]);
    __syncthreads();
    for (int i = t; i < MCH; i += 256) {
        int e = e0 + i;
        if (e < E) {
            int c = col[e];
            int b = c >> CSH;
            int p = atomicAdd(&lpos[b], 1);
            ebuf[gbase[b] + p] = make_int2(row[e], c);
        }
    }
}

// ---- scatter pass 2: one workgroup per coarse bucket -> final CSR position.
__global__ void cfinal_k(const int2* __restrict__ ebuf, const int* __restrict__ row_ptr,
                         int* __restrict__ cursor, int* __restrict__ srcS, int N) {
    int b = blockIdx.x;
    int n0 = b << CSH;
    int n1 = n0 + (1 << CSH);
    if (n1 > N) n1 = N;
    int beg = row_ptr[n0];
    int end = row_ptr[n1];              // row_ptr[N] = E covers the tail bucket
    for (int i = beg + threadIdx.x; i < end; i += 256) {
        int2 p = ebuf[i];
        int pos = atomicAdd(&cursor[p.y], 1);
        srcS[pos] = p.x;
    }
}

// ---------- Wt[l][n][k] = bf16( beta_l*convs[l][k][n] + (k==n)*(1-beta_l) ) ----------
// Residual fold: (1-b)s + b(s@W) == s @ ((1-b)I + bW)  (exact) -> epilogue needs no s.
__global__ void wprep_k(const float* __restrict__ convs, short* __restrict__ Wt) {
    int idx = blockIdx.x * 256 + threadIdx.x;
    if (idx >= 8 * 128 * 128) return;
    int l = idx >> 14;
    int r = idx & 16383;
    int k = r >> 7;
    int n = r & 127;                     // n fastest -> coalesced read
    float beta = logf(0.5f / (float)(l + 1) + 1.0f);
    float v = beta * convs[idx] + ((k == n) ? (1.0f - beta) : 0.0f);
    Wt[(l << 14) + (n << 7) + k] = (short)f2bf(v);
}

// Winb[n][k] = bf16(Win[k][n]), n in [0,128), k in [0,256)
__global__ void winprep_k(const float* __restrict__ Win, short* __restrict__ Winb) {
    int idx = blockIdx.x * 256 + threadIdx.x;
    if (idx >= 256 * 128) return;
    int k = idx >> 7;
    int n = idx & 127;
    Winb[n * 256 + k] = (short)f2bf(Win[idx]);
}

// ---------- h0 via MFMA: h0 = relu(x @ W_in + b_in); h0b = bf16(h0), g = bf16(dinv*h0) ----------
// Staging: global_load_lds width=16, fp32 x, XOR-swizzled 16B chunks.
__global__ __launch_bounds__(256) void h0_k(const float* __restrict__ x,
                                            const short* __restrict__ Winb,
                                            const float* __restrict__ bin,
                                            const float* __restrict__ dinv,
                                            ushort_t* __restrict__ h0b,
                                            ushort_t* __restrict__ g,
                                            int N) {
    __shared__ float xsf[NB * 256];          // 32 KB fp32 x-tile
    __shared__ float s_dv[NB];
    int t = threadIdx.x;
    int lane = t & 63, wv = t >> 6;
    int base = blockIdx.x * NB;

    if (t < NB) s_dv[t] = (base + t < N) ? dinv[base + t] : 1.f;

    if (base + NB <= N) {
        const float* xblk = x + (size_t)base * 256;
#pragma unroll
        for (int it = 0; it < 8; it++) {
            int m = wv * 8 + it;
            const float* src = xblk + (size_t)m * 256 + ((lane ^ (m & 7)) << 2);
            __builtin_amdgcn_global_load_lds(
                (const __attribute__((address_space(1))) unsigned int*)src,
                (__attribute__((address_space(3))) unsigned int*)&xsf[m * 256],
                16, 0, 0);
        }
    } else {
        for (int idx = t; idx < NB * 64; idx += 256) {
            int m = idx >> 6;
            int c16 = idx & 63;
            int nn = base + m;
            float4 v = make_float4(0.f, 0.f, 0.f, 0.f);
            if (nn < N) v = *(const float4*)&x[(size_t)nn * 256 + c16 * 4];
            *(float4*)&xsf[m * 256 + ((c16 ^ (m & 7)) << 2)] = v;
        }
    }
    __syncthreads();   // drains vmcnt (gload_lds) before any LDS read

    int mt = (wv & 1) * 16;
    int jb = wv >> 1;
    int lrow = lane & 15;
    int lq = lane >> 4;
    int r = mt + lrow;
    f32x4 acc0 = {0.f, 0.f, 0.f, 0.f};
    f32x4 acc1 = {0.f, 0.f, 0.f, 0.f};
    f32x4 acc2 = {0.f, 0.f, 0.f, 0.f};
    f32x4 acc3 = {0.f, 0.f, 0.f, 0.f};
#pragma unroll
    for (int ks = 0; ks < 8; ks++) {
        int c16a = ks * 8 + lq * 2;          // first 16B chunk of this A-frag
        f32x4 va = *(const f32x4*)&xsf[r * 256 + (((c16a + 0) ^ (r & 7)) << 2)];
        f32x4 vb = *(const f32x4*)&xsf[r * 256 + (((c16a + 1) ^ (r & 7)) << 2)];
        bf16x8 a;
        a[0] = (short)f2bf(va[0]); a[1] = (short)f2bf(va[1]);
        a[2] = (short)f2bf(va[2]); a[3] = (short)f2bf(va[3]);
        a[4] = (short)f2bf(vb[0]); a[5] = (short)f2bf(vb[1]);
        a[6] = (short)f2bf(vb[2]); a[7] = (short)f2bf(vb[3]);
        bf16x8 b0 = *(const bf16x8*)&Winb[((jb + 0) * 16 + lrow) * 256 + ks * 32 + lq * 8];
        bf16x8 b1 = *(const bf16x8*)&Winb[((jb + 2) * 16 + lrow) * 256 + ks * 32 + lq * 8];
        bf16x8 b2 = *(const bf16x8*)&Winb[((jb + 4) * 16 + lrow) * 256 + ks * 32 + lq * 8];
        bf16x8 b3 = *(const bf16x8*)&Winb[((jb + 6) * 16 + lrow) * 256 + ks * 32 + lq * 8];
        acc0 = __builtin_amdgcn_mfma_f32_16x16x32_bf16(a, b0, acc0, 0, 0, 0);
        acc1 = __builtin_amdgcn_mfma_f32_16x16x32_bf16(a, b1, acc1, 0, 0, 0);
        acc2 = __builtin_amdgcn_mfma_f32_16x16x32_bf16(a, b2, acc2, 0, 0, 0);
        acc3 = __builtin_amdgcn_mfma_f32_16x16x32_bf16(a, b3, acc3, 0, 0, 0);
    }

    // ---- epilogue: stage bf16 results in LDS (aliases dead x-tile), coalesced stores ----
    __syncthreads();
    short* sb = (short*)xsf;
#pragma unroll
    for (int q = 0; q < 4; q++) {
        f32x4 accq = (q == 0) ? acc0 : (q == 1) ? acc1 : (q == 2) ? acc2 : acc3;
        int j0 = (jb + 2 * q) * 16;
        float bj = bin[j0 + lrow];
#pragma unroll
        for (int rr = 0; rr < 4; rr++) {
            int rowm = mt + lq * 4 + rr;         // C/D: col=lane&15, row=quad*4+reg
            float h = fmaxf(accq[rr] + bj, 0.f);
            sb[rowm * SBST + j0 + lrow] = (short)f2bf(h);
            sb[GOFF + rowm * SBST + j0 + lrow] = (short)f2bf(s_dv[rowm] * h);
        }
    }
    __syncthreads();
    for (int idx = t; idx < NB * 16; idx += 256) {
        int rowm = idx >> 4;
        int c = (idx & 15) * 8;
        int dst = base + rowm;
        if (dst < N) {
            *(bf16x8*)&h0b[(size_t)dst * HID + c] = *(const bf16x8*)&sb[rowm * SBST + c];
            *(bf16x8*)&g[(size_t)dst * HID + c]   = *(const bf16x8*)&sb[GOFF + rowm * SBST + c];
        }
    }
}

// ---------- fused layer (g-space): T = g[dst] + sum_nbr g[src];
// s = 0.9*dinv[dst]*T + 0.1*h0 ; h_next = relu(s @ W') ; g_out = bf16(dinv*h_next)
// Gather: per 16-edge round, 16x global_load_lds (width=4) stage full 256B rows
// into a per-wave LDS slab — zero dest VGPRs, HW-guaranteed 16-deep in flight.
// Slots clamp-padded to 16 (dups of last edge), corrected from the slab itself.
__global__ __launch_bounds__(256, 4) void layer_k(const ushort_t* __restrict__ g_in,
                                                  ushort_t* __restrict__ g_out,
                                                  const ushort_t* __restrict__ h0b,
                                                  const float* __restrict__ dinv,
                                                  const int* __restrict__ row_ptr,
                                                  const int* __restrict__ srcS,
                                                  const short* __restrict__ Wtb,
                                                  int N) {
    __shared__ short slab[4][16 * 128]; // 16 KB — per-wave gather slabs (16 rows each)
    __shared__ int   s_idx[CAP];        // 4 KB — block's staged edge list
    __shared__ int   s_rp[NB + 1];
    __shared__ short s_bf[NB * SBST];   // 8.7 KB — bf16 s for MFMA A-frags, then out-staging
    __shared__ float s_dv[NB];
    int t = threadIdx.x;
    int lane = t & 63;
    int wv = t >> 6;
    int base = blockIdx.x * NB;

    if (t < NB + 1) s_rp[t] = row_ptr[min(base + t, N)];
    if (t < NB) s_dv[t] = (base + t < N) ? dinv[base + t] : 1.f;
    int blk_beg = row_ptr[base];
    int blk_end = row_ptr[min(base + NB, N)];
    int nE = blk_end - blk_beg;
    int nL = nE < CAP ? nE : CAP;
    for (int i = t; i < nL; i += 256) s_idx[i] = srcS[blk_beg + i];   // coalesced
    __syncthreads();

    const char* gbp = (const char*)g_in;
    const char* lanebase = gbp + (lane << 2);   // per-lane 4B offset within a row
    short* myslab = &slab[wv][0];

    for (int m = wv; m < NB; m += 4) {
        int dst = base + m;
        if (dst >= N) {
            *(uint32*)&s_bf[m * SBST + lane * 2] = 0;
            continue;
        }
        float dv = s_dv[m];
        uint32 gd = ((const uint32*)(g_in + (size_t)dst * HID))[lane];   // self
        uint32 hu = ((const uint32*)(h0b + (size_t)dst * HID))[lane];    // h0
        float a0 = bf_lo(gd), a1 = bf_hi(gd);
        int beg = s_rp[m], end = s_rp[m + 1];
        int deg = end - beg;
        bool fastp = (end - blk_beg) <= nL;      // ~always true
        if (deg > 0) {
            int nR = (deg + 15) >> 4;
            int eb0 = beg - blk_beg;
            int lastSlot = deg - 1;
            for (int r = 0; r < nR; r++) {
                int s0 = r << 4;
                // issue 16 register-free row-gathers (all in flight)
#pragma unroll
                for (int j = 0; j < 16; j++) {
                    int sl = s0 + j;
                    if (sl > lastSlot) sl = lastSlot;      // clamp dup (corrected below)
                    int idx = fastp ? s_idx[eb0 + sl] : srcS[beg + sl];
                    const char* src = lanebase + ((size_t)(uint32)idx << 8);
                    __builtin_amdgcn_global_load_lds(
                        (const __attribute__((address_space(1))) unsigned int*)src,
                        (__attribute__((address_space(3))) unsigned int*)&myslab[j * 128],
                        4, 0, 0);
                }
                asm volatile("s_waitcnt vmcnt(0)" ::: "memory");
                __builtin_amdgcn_sched_barrier(0);
                // accumulate 16 rows from LDS (conflict-free: 64 lanes stride-1)
#pragma unroll
                for (int j = 0; j < 16; j++) {
                    uint32 v = *(const uint32*)&myslab[j * 128 + lane * 2];
                    a0 += bf_lo(v); a1 += bf_hi(v);
                }
                __builtin_amdgcn_sched_barrier(0);  // keep next-round issues after reads
            }
            int cnt = (nR << 4) - deg;
            if (cnt > 0) {    // subtract the duplicated last-edge contributions
                uint32 v = *(const uint32*)&myslab[(lastSlot & 15) * 128 + lane * 2];
                float fc = (float)cnt;
                a0 -= fc * bf_lo(v);
                a1 -= fc * bf_hi(v);
            }
        }
        float sc = 0.9f * dv;
        float sx = sc * a0 + 0.1f * bf_lo(hu);
        float sy = sc * a1 + 0.1f * bf_hi(hu);
        uint32 pk = ((uint32)f2bf(sy) << 16) | (uint32)f2bf(sx);
        *(uint32*)&s_bf[m * SBST + lane * 2] = pk;
    }
    __syncthreads();

    // ---- Phase B: y = s @ W' via MFMA 16x16x32 bf16 (residual folded into W') ----
    int mt = (wv & 1) * 16;
    int jb = wv >> 1;
    int lrow = lane & 15;
    int lq = lane >> 4;
    f32x4 acc0 = {0.f, 0.f, 0.f, 0.f};
    f32x4 acc1 = {0.f, 0.f, 0.f, 0.f};
    f32x4 acc2 = {0.f, 0.f, 0.f, 0.f};
    f32x4 acc3 = {0.f, 0.f, 0.f, 0.f};
#pragma unroll
    for (int ks = 0; ks < 4; ks++) {
        bf16x8 a = *(const bf16x8*)&s_bf[(mt + lrow) * SBST + ks * 32 + lq * 8];
        bf16x8 b0 = *(const bf16x8*)&Wtb[((jb + 0) * 16 + lrow) * 128 + ks * 32 + lq * 8];
        bf16x8 b1 = *(const bf16x8*)&Wtb[((jb + 2) * 16 + lrow) * 128 + ks * 32 + lq * 8];
        bf16x8 b2 = *(const bf16x8*)&Wtb[((jb + 4) * 16 + lrow) * 128 + ks * 32 + lq * 8];
        bf16x8 b3 = *(const bf16x8*)&Wtb[((jb + 6) * 16 + lrow) * 128 + ks * 32 + lq * 8];
        acc0 = __builtin_amdgcn_mfma_f32_16x16x32_bf16(a, b0, acc0, 0, 0, 0);
        acc1 = __builtin_amdgcn_mfma_f32_16x16x32_bf16(a, b1, acc1, 0, 0, 0);
        acc2 = __builtin_amdgcn_mfma_f32_16x16x32_bf16(a, b2, acc2, 0, 0, 0);
        acc3 = __builtin_amdgcn_mfma_f32_16x16x32_bf16(a, b3, acc3, 0, 0, 0);
    }

    // ---- epilogue: h = relu(acc); stage bf16 g_out in s_bf, coalesced stores ----
    __syncthreads();
#pragma unroll
    for (int q = 0; q < 4; q++) {
        f32x4 accq = (q == 0) ? acc0 : (q == 1) ? acc1 : (q == 2) ? acc2 : acc3;
        int j0 = (jb + 2 * q) * 16;
#pragma unroll
        for (int r = 0; r < 4; r++) {
            int rowm = mt + lq * 4 + r;          // C/D: col=lane&15, row=quad*4+reg
            float h = fmaxf(accq[r], 0.f);
            s_bf[rowm * SBST + j0 + lrow] = (short)f2bf(s_dv[rowm] * h);
        }
    }
    __syncthreads();
    for (int idx = t; idx < NB * 16; idx += 256) {
        int rowm = idx >> 4;
        int cc = (idx & 15) * 8;
        int dst = base + rowm;
        if (dst < N)
            *(bf16x8*)&g_out[(size_t)dst * HID + cc] = *(const bf16x8*)&s_bf[rowm * SBST + cc];
    }
}

// ---------- out = (g/dinv) @ W_out + b_out ----------
__global__ void out_k(const ushort_t* __restrict__ g, const float* __restrict__ dinv,
                      const float* __restrict__ Wout, const float* __restrict__ bout,
                      float* __restrict__ out, int N) {
    int t = threadIdx.x;
    int lane = t & 63;
    int wv = t >> 6;  // 4 waves/block, one node each
    int n = blockIdx.x * 4 + wv;
    if (n >= N) return;
    uint32 u = ((const uint32*)(g + (size_t)n * HID))[lane];
    float v = bf_lo(u) * Wout[lane * 2] + bf_hi(u) * Wout[lane * 2 + 1];
#pragma unroll
    for (int off = 32; off > 0; off >>= 1) v += __shfl_down(v, off, 64);
    if (lane == 0) out[n] = v / dinv[n] + bout[0];
}

extern "C" void kernel_launch(void* const* d_in, const int* in_sizes, int n_in,
                              void* d_out, int out_size, void* d_ws, size_t ws_size,
                              hipStream_t stream) {
    const float* x    = (const float*)d_in[0];
    const int*   ei   = (const int*)d_in[1];
    const float* Win  = (const float*)d_in[2];
    const float* bin  = (const float*)d_in[3];
    const float* convs= (const float*)d_in[4];
    const float* Wout = (const float*)d_in[5];
    const float* bout = (const float*)d_in[6];

    int N = in_sizes[0] / 256;
    int E = in_sizes[1] / 2;
    const int* row = ei;       // sources
    const int* col = ei + E;   // destinations

    char* ws = (char*)d_ws;
    size_t off = 0;
    auto alloc = [&](size_t bytes) -> char* {
        char* p = ws + off;
        off = (off + bytes + 255) & ~(size_t)255;
        return p;
    };
    int NCO = (N + (1 << CSH) - 1) >> CSH;      // 512-node coarse buckets (196)
    int*      counts    = (int*)alloc((size_t)N * 4);
    int*      row_ptr   = (int*)alloc((size_t)(N + 1) * 4);
    int*      cursor    = (int*)alloc((size_t)N * 4);
    int*      ccursor   = (int*)alloc((size_t)NCO * 4);
    int*      blocksums = (int*)alloc(512 * 4);
    int*      blockoffs = (int*)alloc(512 * 4);
    float*    dinv      = (float*)alloc((size_t)N * 4);
    int*      srcS      = (int*)alloc((size_t)E * 4);
    short*    Wt        = (short*)alloc((size_t)8 * 128 * 128 * 2);
    short*    Winb      = (short*)alloc((size_t)256 * 128 * 2);
    ushort_t* h0b       = (ushort_t*)alloc((size_t)N * HID * 2);
    ushort_t* gA        = (ushort_t*)alloc((size_t)N * HID * 2);
    ushort_t* gB        = (ushort_t*)alloc((size_t)N * HID * 2);
    // ebuf (E int2 = 12.8 MB) aliases gB: consumed before h0_k; gB first
    // written by layer 0. Stream-ordered, so no overlap in lifetime.
    int2*     ebuf      = (int2*)gB;

    int eb = (E + 255) / 256;
    int nb = (N + 255) / 256;
    int mb = (E + MCH - 1) / MCH;

    hipMemsetAsync(counts, 0, (size_t)N * 4, stream);
    degree_k<<<eb, 256, 0, stream>>>(col, counts, E);
    scan1_k<<<nb, 256, 0, stream>>>(counts, row_ptr, blocksums, dinv, N);
    scan2_k<<<1, 512, 0, stream>>>(blocksums, blockoffs, nb);
    scan3_k<<<nb, 256, 0, stream>>>(row_ptr, cursor, ccursor, blockoffs, N, E);
    multisplit_k<<<mb, 256, 0, stream>>>(row, col, ccursor, ebuf, E, NCO);
    cfinal_k<<<NCO, 256, 0, stream>>>(ebuf, row_ptr, cursor, srcS, N);
    wprep_k<<<512, 256, 0, stream>>>(convs, Wt);
    winprep_k<<<128, 256, 0, stream>>>(Win, Winb);

    int gb = (N + NB - 1) / NB;
    h0_k<<<gb, 256, 0, stream>>>(x, Winb, bin, dinv, h0b, gA, N);

    ushort_t* gin = gA;
    ushort_t* gout = gB;
    for (int i = 0; i < 8; i++) {
        layer_k<<<gb, 256, 0, stream>>>(gin, gout, h0b, dinv, row_ptr, srcS,
                                        Wt + (size_t)i * 128 * 128, N);
        ushort_t* tp = gin; gin = gout; gout = tp;
    }
    out_k<<<(N + 3) / 4, 256, 0, stream>>>(gin, dinv, Wout, bout, (float*)d_out, N);
}

// Round 11
// 1797.662 us; speedup vs baseline: 1.2006x; 1.2006x over previous
//
#include <hip/hip_runtime.h>
#include <math.h>

#define HID 128
#define NB 32     // nodes per block
#define SBST 136  // padded bf16 row stride for s_bf (16B-aligned, 2-way banks)
#define CSH 9     // coarse bucket = dst >> CSH (512 nodes/bucket); NCO must be <=512
#define MCH 8192  // edges per multisplit block
#define GOFF (32 * SBST)   // h0_k epilogue: g-staging offset inside LDS
#define CAP 1024  // per-block staged edge capacity (mean 512, +22 sigma safe)

typedef unsigned int uint32;
typedef unsigned short ushort_t;
typedef __attribute__((ext_vector_type(8))) short bf16x8;
typedef __attribute__((ext_vector_type(4))) float f32x4;

__device__ __forceinline__ unsigned short f2bf(float f) {
    unsigned u = __float_as_uint(f);
    u += 0x7FFF + ((u >> 16) & 1);          // round-to-nearest-even
    return (unsigned short)(u >> 16);
}
__device__ __forceinline__ float bf_lo(uint32 u) { return __uint_as_float(u << 16); }
__device__ __forceinline__ float bf_hi(uint32 u) { return __uint_as_float(u & 0xFFFF0000u); }

// ---------- CSR build (bucket-level only; per-node work moves to cfinal2's LDS) ----------
__global__ void bcount_k(const int* __restrict__ col, int* __restrict__ bcnt, int E) {
    int e = blockIdx.x * 256 + threadIdx.x;
    if (e < E) atomicAdd(&bcnt[col[e] >> CSH], 1);   // 196 hot counters (L2-resident)
}

// one-block exclusive scan over NCO (<=512) bucket counts
__global__ void bscan_k(const int* __restrict__ bcnt, int* __restrict__ bstart,
                        int* __restrict__ ccursor, int nco, int E) {
    __shared__ int tmp[512];
    int t = threadIdx.x;
    int v = (t < nco) ? bcnt[t] : 0;
    tmp[t] = v;
    __syncthreads();
    for (int off = 1; off < 512; off <<= 1) {
        int x = (t >= off) ? tmp[t - off] : 0;
        __syncthreads();
        tmp[t] += x;
        __syncthreads();
    }
    if (t < nco) {
        bstart[t] = tmp[t] - v;
        ccursor[t] = tmp[t] - v;
    }
    if (t == 0) bstart[nco] = E;
}

// ---- scatter pass 1: block-aggregated multisplit into coarse buckets.
// One global atomic per (block,bucket) reserves a CONTIGUOUS region; all stores
// in a region come from one block (one CU -> one XCD) so L2 lines fill fully.
__global__ __launch_bounds__(256) void multisplit_k(const int* __restrict__ row,
                                                    const int* __restrict__ col,
                                                    int* __restrict__ ccursor,
                                                    int2* __restrict__ ebuf,
                                                    int E, int NCO) {
    __shared__ int lcnt[256];
    __shared__ int gbase[256];
    __shared__ int lpos[256];
    int t = threadIdx.x;
    int e0 = blockIdx.x * MCH;
    lcnt[t] = 0;
    lpos[t] = 0;
    __syncthreads();
    for (int i = t; i < MCH; i += 256) {
        int e = e0 + i;
        if (e < E) atomicAdd(&lcnt[col[e] >> CSH], 1);
    }
    __syncthreads();
    if (t < NCO && lcnt[t] > 0) gbase[t] = atomicAdd(&ccursor[t], lcnt[t]);
    __syncthreads();
    for (int i = t; i < MCH; i += 256) {
        int e = e0 + i;
        if (e < E) {
            int c = col[e];
            int b = c >> CSH;
            int p = atomicAdd(&lpos[b], 1);
            ebuf[gbase[b] + p] = make_int2(row[e], c);
        }
    }
}

// ---- pass 2: per bucket, derive per-node degree/row_ptr/dinv/cursor in LDS,
// then scatter to final CSR position. Replaces degree_k + scan1/2/3 entirely.
__global__ void cfinal2_k(const int2* __restrict__ ebuf, const int* __restrict__ bstart,
                          int* __restrict__ row_ptr, float* __restrict__ dinv,
                          int* __restrict__ srcS, int N, int E) {
    __shared__ int cnt[512];
    __shared__ int tmp[256];
    __shared__ int curs[512];
    int t = threadIdx.x;
    int b = blockIdx.x;
    int n0 = b << CSH;
    int beg = bstart[b];
    int end = bstart[b + 1];
    cnt[t] = 0;
    cnt[t + 256] = 0;
    __syncthreads();
    for (int i = beg + t; i < end; i += 256)
        atomicAdd(&cnt[ebuf[i].y & 511], 1);
    __syncthreads();
    int c0 = cnt[2 * t], c1 = cnt[2 * t + 1];
    int psum = c0 + c1;
    tmp[t] = psum;
    __syncthreads();
    for (int off = 1; off < 256; off <<= 1) {
        int x = (t >= off) ? tmp[t - off] : 0;
        __syncthreads();
        tmp[t] += x;
        __syncthreads();
    }
    int exc0 = tmp[t] - psum;
    int exc1 = exc0 + c0;
    int na = n0 + 2 * t, nb_ = n0 + 2 * t + 1;
    if (na < N) { row_ptr[na] = beg + exc0; dinv[na] = rsqrtf((float)c0 + 1.f); }
    if (nb_ < N) { row_ptr[nb_] = beg + exc1; dinv[nb_] = rsqrtf((float)c1 + 1.f); }
    curs[2 * t] = beg + exc0;
    curs[2 * t + 1] = beg + exc1;
    if (b == 0 && t == 0) row_ptr[N] = E;
    __syncthreads();
    for (int i = beg + t; i < end; i += 256) {
        int2 p = ebuf[i];
        int pos = atomicAdd(&curs[p.y & 511], 1);
        srcS[pos] = p.x;
    }
}

// ---------- Wt[l][n][k] = bf16( beta_l*convs[l][k][n] + (k==n)*(1-beta_l) ) ----------
__global__ void wprep_k(const float* __restrict__ convs, short* __restrict__ Wt) {
    int idx = blockIdx.x * 256 + threadIdx.x;
    if (idx >= 8 * 128 * 128) return;
    int l = idx >> 14;
    int r = idx & 16383;
    int k = r >> 7;
    int n = r & 127;                     // n fastest -> coalesced read
    float beta = logf(0.5f / (float)(l + 1) + 1.0f);
    float v = beta * convs[idx] + ((k == n) ? (1.0f - beta) : 0.0f);
    Wt[(l << 14) + (n << 7) + k] = (short)f2bf(v);
}

// Winb[n][k] = bf16(Win[k][n]), n in [0,128), k in [0,256)
__global__ void winprep_k(const float* __restrict__ Win, short* __restrict__ Winb) {
    int idx = blockIdx.x * 256 + threadIdx.x;
    if (idx >= 256 * 128) return;
    int k = idx >> 7;
    int n = idx & 127;
    Winb[n * 256 + k] = (short)f2bf(Win[idx]);
}

// ---------- h0 via MFMA: h0 = relu(x @ W_in + b_in); h0b = bf16(h0), g = bf16(dinv*h0) ----------
// Staging: global_load_lds width=16, fp32 x, XOR-swizzled 16B chunks (rule #21).
__global__ __launch_bounds__(256) void h0_k(const float* __restrict__ x,
                                            const short* __restrict__ Winb,
                                            const float* __restrict__ bin,
                                            const float* __restrict__ dinv,
                                            ushort_t* __restrict__ h0b,
                                            ushort_t* __restrict__ g,
                                            int N) {
    __shared__ float xsf[NB * 256];          // 32 KB fp32 x-tile
    __shared__ float s_dv[NB];
    int t = threadIdx.x;
    int lane = t & 63, wv = t >> 6;
    int base = blockIdx.x * NB;

    if (t < NB) s_dv[t] = (base + t < N) ? dinv[base + t] : 1.f;

    if (base + NB <= N) {
        const float* xblk = x + (size_t)base * 256;
#pragma unroll
        for (int it = 0; it < 8; it++) {
            int m = wv * 8 + it;
            const float* src = xblk + (size_t)m * 256 + ((lane ^ (m & 7)) << 2);
            __builtin_amdgcn_global_load_lds(
                (const __attribute__((address_space(1))) unsigned int*)src,
                (__attribute__((address_space(3))) unsigned int*)&xsf[m * 256],
                16, 0, 0);
        }
    } else {
        for (int idx = t; idx < NB * 64; idx += 256) {
            int m = idx >> 6;
            int c16 = idx & 63;
            int nn = base + m;
            float4 v = make_float4(0.f, 0.f, 0.f, 0.f);
            if (nn < N) v = *(const float4*)&x[(size_t)nn * 256 + c16 * 4];
            *(float4*)&xsf[m * 256 + ((c16 ^ (m & 7)) << 2)] = v;
        }
    }
    __syncthreads();   // drains vmcnt (gload_lds) before any LDS read

    int mt = (wv & 1) * 16;
    int jb = wv >> 1;
    int lrow = lane & 15;
    int lq = lane >> 4;
    int r = mt + lrow;
    f32x4 acc0 = {0.f, 0.f, 0.f, 0.f};
    f32x4 acc1 = {0.f, 0.f, 0.f, 0.f};
    f32x4 acc2 = {0.f, 0.f, 0.f, 0.f};
    f32x4 acc3 = {0.f, 0.f, 0.f, 0.f};
#pragma unroll
    for (int ks = 0; ks < 8; ks++) {
        int c16a = ks * 8 + lq * 2;          // first 16B chunk of this A-frag
        f32x4 va = *(const f32x4*)&xsf[r * 256 + (((c16a + 0) ^ (r & 7)) << 2)];
        f32x4 vb = *(const f32x4*)&xsf[r * 256 + (((c16a + 1) ^ (r & 7)) << 2)];
        bf16x8 a;
        a[0] = (short)f2bf(va[0]); a[1] = (short)f2bf(va[1]);
        a[2] = (short)f2bf(va[2]); a[3] = (short)f2bf(va[3]);
        a[4] = (short)f2bf(vb[0]); a[5] = (short)f2bf(vb[1]);
        a[6] = (short)f2bf(vb[2]); a[7] = (short)f2bf(vb[3]);
        bf16x8 b0 = *(const bf16x8*)&Winb[((jb + 0) * 16 + lrow) * 256 + ks * 32 + lq * 8];
        bf16x8 b1 = *(const bf16x8*)&Winb[((jb + 2) * 16 + lrow) * 256 + ks * 32 + lq * 8];
        bf16x8 b2 = *(const bf16x8*)&Winb[((jb + 4) * 16 + lrow) * 256 + ks * 32 + lq * 8];
        bf16x8 b3 = *(const bf16x8*)&Winb[((jb + 6) * 16 + lrow) * 256 + ks * 32 + lq * 8];
        acc0 = __builtin_amdgcn_mfma_f32_16x16x32_bf16(a, b0, acc0, 0, 0, 0);
        acc1 = __builtin_amdgcn_mfma_f32_16x16x32_bf16(a, b1, acc1, 0, 0, 0);
        acc2 = __builtin_amdgcn_mfma_f32_16x16x32_bf16(a, b2, acc2, 0, 0, 0);
        acc3 = __builtin_amdgcn_mfma_f32_16x16x32_bf16(a, b3, acc3, 0, 0, 0);
    }

    // ---- epilogue: stage bf16 results in LDS (aliases dead x-tile), coalesced stores ----
    __syncthreads();
    short* sb = (short*)xsf;
#pragma unroll
    for (int q = 0; q < 4; q++) {
        f32x4 accq = (q == 0) ? acc0 : (q == 1) ? acc1 : (q == 2) ? acc2 : acc3;
        int j0 = (jb + 2 * q) * 16;
        float bj = bin[j0 + lrow];
#pragma unroll
        for (int rr = 0; rr < 4; rr++) {
            int rowm = mt + lq * 4 + rr;         // C/D: col=lane&15, row=quad*4+reg
            float h = fmaxf(accq[rr] + bj, 0.f);
            sb[rowm * SBST + j0 + lrow] = (short)f2bf(h);
            sb[GOFF + rowm * SBST + j0 + lrow] = (short)f2bf(s_dv[rowm] * h);
        }
    }
    __syncthreads();
    for (int idx = t; idx < NB * 16; idx += 256) {
        int rowm = idx >> 4;
        int c = (idx & 15) * 8;
        int dst = base + rowm;
        if (dst < N) {
            *(bf16x8*)&h0b[(size_t)dst * HID + c] = *(const bf16x8*)&sb[rowm * SBST + c];
            *(bf16x8*)&g[(size_t)dst * HID + c]   = *(const bf16x8*)&sb[GOFF + rowm * SBST + c];
        }
    }
}

// ---------- fused layer (g-space): T = g[dst] + sum_nbr g[src];
// s = 0.9*dinv[dst]*T + 0.1*h0 ; h_next = relu(s @ W') ; g_out = bf16(dinv*h_next)
// Gather = r7 structure (LDS indices, 16 uint32 gathers/round) with scalar
// clamp-and-correct tail (no per-slot guards). Last layer (Wout != null):
// fused output dot, no g_out write.
__global__ __launch_bounds__(256, 4) void layer_k(const ushort_t* __restrict__ g_in,
                                                  ushort_t* __restrict__ g_out,
                                                  const ushort_t* __restrict__ h0b,
                                                  const float* __restrict__ dinv,
                                                  const int* __restrict__ row_ptr,
                                                  const int* __restrict__ srcS,
                                                  const short* __restrict__ Wtb,
                                                  int N,
                                                  const float* __restrict__ Wout,
                                                  const float* __restrict__ bout,
                                                  float* __restrict__ outp) {
    __shared__ int   s_idx[CAP];        // 4 KB — block's staged edge list
    __shared__ int   s_rp[NB + 1];
    __shared__ short s_bf[NB * SBST];   // 8.7 KB — bf16 s for MFMA A-frags, then staging
    __shared__ float s_dv[NB];
    int t = threadIdx.x;
    int lane = t & 63;
    int wv = t >> 6;
    int base = blockIdx.x * NB;

    if (t < NB + 1) s_rp[t] = row_ptr[min(base + t, N)];
    if (t < NB) s_dv[t] = (base + t < N) ? dinv[base + t] : 1.f;
    int blk_beg = row_ptr[base];
    int blk_end = row_ptr[min(base + NB, N)];
    int nE = blk_end - blk_beg;
    int nL = nE < CAP ? nE : CAP;
    for (int i = t; i < nL; i += 256) s_idx[i] = srcS[blk_beg + i];   // coalesced
    __syncthreads();

    const char* gbp = (const char*)g_in;
    uint32 lb = (uint32)(lane << 2);
    for (int m = wv; m < NB; m += 4) {
        int dst = base + m;
        if (dst >= N) {
            *(uint32*)&s_bf[m * SBST + lane * 2] = 0;
            continue;
        }
        float dv = s_dv[m];
        uint32 gd = ((const uint32*)(g_in + (size_t)dst * HID))[lane];   // self
        uint32 hu = ((const uint32*)(h0b + (size_t)dst * HID))[lane];    // h0
        float ax = bf_lo(gd), ay = bf_hi(gd);
        int beg = s_rp[m], end = s_rp[m + 1];
        int deg = end - beg;
        if (deg > 0) {
            int nR = (deg + 15) >> 4;
            bool fastp = (end - blk_beg) <= nL;      // ~always true
            if (fastp) {
                int eb0 = beg - blk_beg;
                int lastI = eb0 + deg - 1;
                for (int r = 0; r < nR; r++) {
                    int e = eb0 + (r << 4);          // slots clamped (scalar min)
                    int i0  = s_idx[min(e + 0,  lastI)];
                    int i1  = s_idx[min(e + 1,  lastI)];
                    int i2  = s_idx[min(e + 2,  lastI)];
                    int i3  = s_idx[min(e + 3,  lastI)];
                    int i4  = s_idx[min(e + 4,  lastI)];
                    int i5  = s_idx[min(e + 5,  lastI)];
                    int i6  = s_idx[min(e + 6,  lastI)];
                    int i7  = s_idx[min(e + 7,  lastI)];
                    int i8  = s_idx[min(e + 8,  lastI)];
                    int i9  = s_idx[min(e + 9,  lastI)];
                    int i10 = s_idx[min(e + 10, lastI)];
                    int i11 = s_idx[min(e + 11, lastI)];
                    int i12 = s_idx[min(e + 12, lastI)];
                    int i13 = s_idx[min(e + 13, lastI)];
                    int i14 = s_idx[min(e + 14, lastI)];
                    int i15 = s_idx[min(e + 15, lastI)];
                    uint32 g0  = *(const uint32*)(gbp + (((uint32)i0  << 8) | lb));
                    uint32 g1  = *(const uint32*)(gbp + (((uint32)i1  << 8) | lb));
                    uint32 g2  = *(const uint32*)(gbp + (((uint32)i2  << 8) | lb));
                    uint32 g3  = *(const uint32*)(gbp + (((uint32)i3  << 8) | lb));
                    uint32 g4  = *(const uint32*)(gbp + (((uint32)i4  << 8) | lb));
                    uint32 g5  = *(const uint32*)(gbp + (((uint32)i5  << 8) | lb));
                    uint32 g6  = *(const uint32*)(gbp + (((uint32)i6  << 8) | lb));
                    uint32 g7  = *(const uint32*)(gbp + (((uint32)i7  << 8) | lb));
                    uint32 g8  = *(const uint32*)(gbp + (((uint32)i8  << 8) | lb));
                    uint32 g9  = *(const uint32*)(gbp + (((uint32)i9  << 8) | lb));
                    uint32 g10 = *(const uint32*)(gbp + (((uint32)i10 << 8) | lb));
                    uint32 g11 = *(const uint32*)(gbp + (((uint32)i11 << 8) | lb));
                    uint32 g12 = *(const uint32*)(gbp + (((uint32)i12 << 8) | lb));
                    uint32 g13 = *(const uint32*)(gbp + (((uint32)i13 << 8) | lb));
                    uint32 g14 = *(const uint32*)(gbp + (((uint32)i14 << 8) | lb));
                    uint32 g15 = *(const uint32*)(gbp + (((uint32)i15 << 8) | lb));
                    ax += bf_lo(g0);  ay += bf_hi(g0);
                    ax += bf_lo(g1);  ay += bf_hi(g1);
                    ax += bf_lo(g2);  ay += bf_hi(g2);
                    ax += bf_lo(g3);  ay += bf_hi(g3);
                    ax += bf_lo(g4);  ay += bf_hi(g4);
                    ax += bf_lo(g5);  ay += bf_hi(g5);
                    ax += bf_lo(g6);  ay += bf_hi(g6);
                    ax += bf_lo(g7);  ay += bf_hi(g7);
                    ax += bf_lo(g8);  ay += bf_hi(g8);
                    ax += bf_lo(g9);  ay += bf_hi(g9);
                    ax += bf_lo(g10); ay += bf_hi(g10);
                    ax += bf_lo(g11); ay += bf_hi(g11);
                    ax += bf_lo(g12); ay += bf_hi(g12);
                    ax += bf_lo(g13); ay += bf_hi(g13);
                    ax += bf_lo(g14); ay += bf_hi(g14);
                    ax += bf_lo(g15); ay += bf_hi(g15);
                }
                if (deg & 15) {      // subtract duplicated last-edge contributions
                    int cnt = (nR << 4) - deg;
                    uint32 gl = *(const uint32*)(gbp + (((uint32)s_idx[lastI] << 8) | lb));
                    float fc = (float)cnt;
                    ax -= fc * bf_lo(gl);
                    ay -= fc * bf_hi(gl);
                }
            } else {
                // fallback (statistically unreachable): indices from global srcS
                int lastA = end - 1;
                for (int r = 0; r < nR; r++) {
                    int e = beg + (r << 4);
#pragma unroll
                    for (int k = 0; k < 16; k++) {
                        int sn = srcS[min(e + k, lastA)];
                        uint32 gg = *(const uint32*)(gbp + (((uint32)sn << 8) | lb));
                        ax += bf_lo(gg); ay += bf_hi(gg);
                    }
                }
                if (deg & 15) {
                    int cnt = (nR << 4) - deg;
                    uint32 gl = *(const uint32*)(gbp + (((uint32)srcS[lastA] << 8) | lb));
                    float fc = (float)cnt;
                    ax -= fc * bf_lo(gl);
                    ay -= fc * bf_hi(gl);
                }
            }
        }
        float sc = 0.9f * dv;
        float sx = sc * ax + 0.1f * bf_lo(hu);
        float sy = sc * ay + 0.1f * bf_hi(hu);
        uint32 pk = ((uint32)f2bf(sy) << 16) | (uint32)f2bf(sx);
        *(uint32*)&s_bf[m * SBST + lane * 2] = pk;
    }
    __syncthreads();

    // ---- Phase B: y = s @ W' via MFMA 16x16x32 bf16 (residual folded into W') ----
    int mt = (wv & 1) * 16;
    int jb = wv >> 1;
    int lrow = lane & 15;
    int lq = lane >> 4;
    f32x4 acc0 = {0.f, 0.f, 0.f, 0.f};
    f32x4 acc1 = {0.f, 0.f, 0.f, 0.f};
    f32x4 acc2 = {0.f, 0.f, 0.f, 0.f};
    f32x4 acc3 = {0.f, 0.f, 0.f, 0.f};
#pragma unroll
    for (int ks = 0; ks < 4; ks++) {
        bf16x8 a = *(const bf16x8*)&s_bf[(mt + lrow) * SBST + ks * 32 + lq * 8];
        bf16x8 b0 = *(const bf16x8*)&Wtb[((jb + 0) * 16 + lrow) * 128 + ks * 32 + lq * 8];
        bf16x8 b1 = *(const bf16x8*)&Wtb[((jb + 2) * 16 + lrow) * 128 + ks * 32 + lq * 8];
        bf16x8 b2 = *(const bf16x8*)&Wtb[((jb + 4) * 16 + lrow) * 128 + ks * 32 + lq * 8];
        bf16x8 b3 = *(const bf16x8*)&Wtb[((jb + 6) * 16 + lrow) * 128 + ks * 32 + lq * 8];
        acc0 = __builtin_amdgcn_mfma_f32_16x16x32_bf16(a, b0, acc0, 0, 0, 0);
        acc1 = __builtin_amdgcn_mfma_f32_16x16x32_bf16(a, b1, acc1, 0, 0, 0);
        acc2 = __builtin_amdgcn_mfma_f32_16x16x32_bf16(a, b2, acc2, 0, 0, 0);
        acc3 = __builtin_amdgcn_mfma_f32_16x16x32_bf16(a, b3, acc3, 0, 0, 0);
    }

    __syncthreads();   // all A-frag reads done before s_bf overwrite
    if (Wout == nullptr) {
        // ---- normal epilogue: g_out = bf16(dinv * relu(acc)), coalesced stores ----
#pragma unroll
        for (int q = 0; q < 4; q++) {
            f32x4 accq = (q == 0) ? acc0 : (q == 1) ? acc1 : (q == 2) ? acc2 : acc3;
            int j0 = (jb + 2 * q) * 16;
#pragma unroll
            for (int r = 0; r < 4; r++) {
                int rowm = mt + lq * 4 + r;      // C/D: col=lane&15, row=quad*4+reg
                float h = fmaxf(accq[r], 0.f);
                s_bf[rowm * SBST + j0 + lrow] = (short)f2bf(s_dv[rowm] * h);
            }
        }
        __syncthreads();
        for (int idx = t; idx < NB * 16; idx += 256) {
            int rowm = idx >> 4;
            int cc = (idx & 15) * 8;
            int dst = base + rowm;
            if (dst < N)
                *(bf16x8*)&g_out[(size_t)dst * HID + cc] = *(const bf16x8*)&s_bf[rowm * SBST + cc];
        }
    } else {
        // ---- fused final output: out[n] = relu(h) . Wout + bout (no g_out write) ----
#pragma unroll
        for (int q = 0; q < 4; q++) {
            f32x4 accq = (q == 0) ? acc0 : (q == 1) ? acc1 : (q == 2) ? acc2 : acc3;
            int j0 = (jb + 2 * q) * 16;
#pragma unroll
            for (int r = 0; r < 4; r++) {
                int rowm = mt + lq * 4 + r;
                s_bf[rowm * SBST + j0 + lrow] = (short)f2bf(fmaxf(accq[r], 0.f));
            }
        }
        __syncthreads();
        float w0 = Wout[lane * 2];
        float w1 = Wout[lane * 2 + 1];
        float bo = bout[0];
        for (int rr = 0; rr < 8; rr++) {
            int rowm = wv * 8 + rr;              // wave wv owns rows wv*8..wv*8+7
            uint32 u = *(const uint32*)&s_bf[rowm * SBST + lane * 2];
            float v = bf_lo(u) * w0 + bf_hi(u) * w1;
#pragma unroll
            for (int off = 32; off > 0; off >>= 1) v += __shfl_down(v, off, 64);
            if (lane == 0 && base + rowm < N) outp[base + rowm] = v + bo;
        }
    }
}

extern "C" void kernel_launch(void* const* d_in, const int* in_sizes, int n_in,
                              void* d_out, int out_size, void* d_ws, size_t ws_size,
                              hipStream_t stream) {
    const float* x    = (const float*)d_in[0];
    const int*   ei   = (const int*)d_in[1];
    const float* Win  = (const float*)d_in[2];
    const float* bin  = (const float*)d_in[3];
    const float* convs= (const float*)d_in[4];
    const float* Wout = (const float*)d_in[5];
    const float* bout = (const float*)d_in[6];

    int N = in_sizes[0] / 256;
    int E = in_sizes[1] / 2;
    const int* row = ei;       // sources
    const int* col = ei + E;   // destinations

    char* ws = (char*)d_ws;
    size_t off = 0;
    auto alloc = [&](size_t bytes) -> char* {
        char* p = ws + off;
        off = (off + bytes + 255) & ~(size_t)255;
        return p;
    };
    int NCO = (N + (1 << CSH) - 1) >> CSH;      // 512-node coarse buckets (196; <=512 req'd)
    int*      row_ptr   = (int*)alloc((size_t)(N + 1) * 4);
    int*      bcnt      = (int*)alloc((size_t)NCO * 4);
    int*      bstart    = (int*)alloc((size_t)(NCO + 1) * 4);
    int*      ccursor   = (int*)alloc((size_t)NCO * 4);
    float*    dinv      = (float*)alloc((size_t)N * 4);
    int*      srcS      = (int*)alloc((size_t)E * 4);
    short*    Wt        = (short*)alloc((size_t)8 * 128 * 128 * 2);
    short*    Winb      = (short*)alloc((size_t)256 * 128 * 2);
    ushort_t* h0b       = (ushort_t*)alloc((size_t)N * HID * 2);
    ushort_t* gA        = (ushort_t*)alloc((size_t)N * HID * 2);
    ushort_t* gB        = (ushort_t*)alloc((size_t)N * HID * 2);
    // ebuf (E int2 = 12.8 MB) aliases gB: consumed in cfinal2 before h0_k; gB
    // first written by layer 0. Stream-ordered, so no overlap in lifetime.
    int2*     ebuf      = (int2*)gB;

    int eb = (E + 255) / 256;
    int mb = (E + MCH - 1) / MCH;

    hipMemsetAsync(bcnt, 0, (size_t)NCO * 4, stream);
    bcount_k<<<eb, 256, 0, stream>>>(col, bcnt, E);
    bscan_k<<<1, 512, 0, stream>>>(bcnt, bstart, ccursor, NCO, E);
    multisplit_k<<<mb, 256, 0, stream>>>(row, col, ccursor, ebuf, E, NCO);
    cfinal2_k<<<NCO, 256, 0, stream>>>(ebuf, bstart, row_ptr, dinv, srcS, N, E);
    wprep_k<<<512, 256, 0, stream>>>(convs, Wt);
    winprep_k<<<128, 256, 0, stream>>>(Win, Winb);

    int gb = (N + NB - 1) / NB;
    h0_k<<<gb, 256, 0, stream>>>(x, Winb, bin, dinv, h0b, gA, N);

    ushort_t* gin = gA;
    ushort_t* gout = gB;
    for (int i = 0; i < 8; i++) {
        bool last = (i == 7);
        layer_k<<<gb, 256, 0, stream>>>(gin, gout, h0b, dinv, row_ptr, srcS,
                                        Wt + (size_t)i * 128 * 128, N,
                                        last ? Wout : nullptr, bout, (float*)d_out);
        ushort_t* tp = gin; gin = gout; gout = tp;
    }
}

// Round 12
// 916.371 us; speedup vs baseline: 2.3552x; 1.9617x over previous
//
#include <hip/hip_runtime.h>
#include <math.h>

#define HID 128
#define NB 32     // nodes per block
#define SBST 136  // padded bf16 row stride for s_bf (16B-aligned, 2-way banks)
#define CSH 9     // coarse bucket = dst >> CSH (512 nodes/bucket); NCO must be <=512
#define MCH 8192  // edges per multisplit block
#define GOFF (32 * SBST)   // h0_k epilogue: g-staging offset inside LDS
#define CAP 1024  // per-block staged edge capacity (mean 512, +22 sigma safe)

typedef unsigned int uint32;
typedef unsigned short ushort_t;
typedef __attribute__((ext_vector_type(8))) short bf16x8;
typedef __attribute__((ext_vector_type(4))) float f32x4;

__device__ __forceinline__ unsigned short f2bf(float f) {
    unsigned u = __float_as_uint(f);
    u += 0x7FFF + ((u >> 16) & 1);          // round-to-nearest-even
    return (unsigned short)(u >> 16);
}
__device__ __forceinline__ float bf_lo(uint32 u) { return __uint_as_float(u << 16); }
__device__ __forceinline__ float bf_hi(uint32 u) { return __uint_as_float(u & 0xFFFF0000u); }

// ---------- CSR build (bucket-level only; per-node work moves to cfinal2's LDS) ----------
// LDS-aggregated bucket count: per-block LDS atomics (private, fast), then
// <=NCO global atomics per block (~196/address total — benign).
// NOTE round-11 lesson: atomic cost scales with OPS-PER-ADDRESS; 1.6M device
// atomics on 196 addresses (no aggregation) was 888 us.
__global__ __launch_bounds__(256) void bcount_k(const int* __restrict__ col,
                                                int* __restrict__ bcnt, int E, int NCO) {
    __shared__ int lcnt[512];
    int t = threadIdx.x;
    lcnt[t] = 0;
    lcnt[t + 256] = 0;
    __syncthreads();
    int e0 = blockIdx.x * MCH;
    for (int i = t; i < MCH; i += 256) {
        int e = e0 + i;
        if (e < E) atomicAdd(&lcnt[col[e] >> CSH], 1);
    }
    __syncthreads();
    if (t < NCO && lcnt[t] > 0) atomicAdd(&bcnt[t], lcnt[t]);
}

// one-block exclusive scan over NCO (<=512) bucket counts
__global__ void bscan_k(const int* __restrict__ bcnt, int* __restrict__ bstart,
                        int* __restrict__ ccursor, int nco, int E) {
    __shared__ int tmp[512];
    int t = threadIdx.x;
    int v = (t < nco) ? bcnt[t] : 0;
    tmp[t] = v;
    __syncthreads();
    for (int off = 1; off < 512; off <<= 1) {
        int x = (t >= off) ? tmp[t - off] : 0;
        __syncthreads();
        tmp[t] += x;
        __syncthreads();
    }
    if (t < nco) {
        bstart[t] = tmp[t] - v;
        ccursor[t] = tmp[t] - v;
    }
    if (t == 0) bstart[nco] = E;
}

// ---- scatter pass 1: block-aggregated multisplit into coarse buckets.
// One global atomic per (block,bucket) reserves a CONTIGUOUS region; all stores
// in a region come from one block (one CU -> one XCD) so L2 lines fill fully.
__global__ __launch_bounds__(256) void multisplit_k(const int* __restrict__ row,
                                                    const int* __restrict__ col,
                                                    int* __restrict__ ccursor,
                                                    int2* __restrict__ ebuf,
                                                    int E, int NCO) {
    __shared__ int lcnt[256];
    __shared__ int gbase[256];
    __shared__ int lpos[256];
    int t = threadIdx.x;
    int e0 = blockIdx.x * MCH;
    lcnt[t] = 0;
    lpos[t] = 0;
    __syncthreads();
    for (int i = t; i < MCH; i += 256) {
        int e = e0 + i;
        if (e < E) atomicAdd(&lcnt[col[e] >> CSH], 1);
    }
    __syncthreads();
    if (t < NCO && lcnt[t] > 0) gbase[t] = atomicAdd(&ccursor[t], lcnt[t]);
    __syncthreads();
    for (int i = t; i < MCH; i += 256) {
        int e = e0 + i;
        if (e < E) {
            int c = col[e];
            int b = c >> CSH;
            int p = atomicAdd(&lpos[b], 1);
            ebuf[gbase[b] + p] = make_int2(row[e], c);
        }
    }
}

// ---- pass 2: per bucket, derive per-node degree/row_ptr/dinv/cursor in LDS,
// then scatter to final CSR position. Replaces degree_k + scan1/2/3 entirely.
__global__ void cfinal2_k(const int2* __restrict__ ebuf, const int* __restrict__ bstart,
                          int* __restrict__ row_ptr, float* __restrict__ dinv,
                          int* __restrict__ srcS, int N, int E) {
    __shared__ int cnt[512];
    __shared__ int tmp[256];
    __shared__ int curs[512];
    int t = threadIdx.x;
    int b = blockIdx.x;
    int n0 = b << CSH;
    int beg = bstart[b];
    int end = bstart[b + 1];
    cnt[t] = 0;
    cnt[t + 256] = 0;
    __syncthreads();
    for (int i = beg + t; i < end; i += 256)
        atomicAdd(&cnt[ebuf[i].y & 511], 1);
    __syncthreads();
    int c0 = cnt[2 * t], c1 = cnt[2 * t + 1];
    int psum = c0 + c1;
    tmp[t] = psum;
    __syncthreads();
    for (int off = 1; off < 256; off <<= 1) {
        int x = (t >= off) ? tmp[t - off] : 0;
        __syncthreads();
        tmp[t] += x;
        __syncthreads();
    }
    int exc0 = tmp[t] - psum;
    int exc1 = exc0 + c0;
    int na = n0 + 2 * t, nb_ = n0 + 2 * t + 1;
    if (na < N) { row_ptr[na] = beg + exc0; dinv[na] = rsqrtf((float)c0 + 1.f); }
    if (nb_ < N) { row_ptr[nb_] = beg + exc1; dinv[nb_] = rsqrtf((float)c1 + 1.f); }
    curs[2 * t] = beg + exc0;
    curs[2 * t + 1] = beg + exc1;
    if (b == 0 && t == 0) row_ptr[N] = E;
    __syncthreads();
    for (int i = beg + t; i < end; i += 256) {
        int2 p = ebuf[i];
        int pos = atomicAdd(&curs[p.y & 511], 1);
        srcS[pos] = p.x;
    }
}

// ---------- Wt[l][n][k] = bf16( beta_l*convs[l][k][n] + (k==n)*(1-beta_l) ) ----------
__global__ void wprep_k(const float* __restrict__ convs, short* __restrict__ Wt) {
    int idx = blockIdx.x * 256 + threadIdx.x;
    if (idx >= 8 * 128 * 128) return;
    int l = idx >> 14;
    int r = idx & 16383;
    int k = r >> 7;
    int n = r & 127;                     // n fastest -> coalesced read
    float beta = logf(0.5f / (float)(l + 1) + 1.0f);
    float v = beta * convs[idx] + ((k == n) ? (1.0f - beta) : 0.0f);
    Wt[(l << 14) + (n << 7) + k] = (short)f2bf(v);
}

// Winb[n][k] = bf16(Win[k][n]), n in [0,128), k in [0,256)
__global__ void winprep_k(const float* __restrict__ Win, short* __restrict__ Winb) {
    int idx = blockIdx.x * 256 + threadIdx.x;
    if (idx >= 256 * 128) return;
    int k = idx >> 7;
    int n = idx & 127;
    Winb[n * 256 + k] = (short)f2bf(Win[idx]);
}

// ---------- h0 via MFMA: h0 = relu(x @ W_in + b_in); h0b = bf16(h0), g = bf16(dinv*h0) ----------
// Staging: global_load_lds width=16, fp32 x, XOR-swizzled 16B chunks (rule #21).
__global__ __launch_bounds__(256) void h0_k(const float* __restrict__ x,
                                            const short* __restrict__ Winb,
                                            const float* __restrict__ bin,
                                            const float* __restrict__ dinv,
                                            ushort_t* __restrict__ h0b,
                                            ushort_t* __restrict__ g,
                                            int N) {
    __shared__ float xsf[NB * 256];          // 32 KB fp32 x-tile
    __shared__ float s_dv[NB];
    int t = threadIdx.x;
    int lane = t & 63, wv = t >> 6;
    int base = blockIdx.x * NB;

    if (t < NB) s_dv[t] = (base + t < N) ? dinv[base + t] : 1.f;

    if (base + NB <= N) {
        const float* xblk = x + (size_t)base * 256;
#pragma unroll
        for (int it = 0; it < 8; it++) {
            int m = wv * 8 + it;
            const float* src = xblk + (size_t)m * 256 + ((lane ^ (m & 7)) << 2);
            __builtin_amdgcn_global_load_lds(
                (const __attribute__((address_space(1))) unsigned int*)src,
                (__attribute__((address_space(3))) unsigned int*)&xsf[m * 256],
                16, 0, 0);
        }
    } else {
        for (int idx = t; idx < NB * 64; idx += 256) {
            int m = idx >> 6;
            int c16 = idx & 63;
            int nn = base + m;
            float4 v = make_float4(0.f, 0.f, 0.f, 0.f);
            if (nn < N) v = *(const float4*)&x[(size_t)nn * 256 + c16 * 4];
            *(float4*)&xsf[m * 256 + ((c16 ^ (m & 7)) << 2)] = v;
        }
    }
    __syncthreads();   // drains vmcnt (gload_lds) before any LDS read

    int mt = (wv & 1) * 16;
    int jb = wv >> 1;
    int lrow = lane & 15;
    int lq = lane >> 4;
    int r = mt + lrow;
    f32x4 acc0 = {0.f, 0.f, 0.f, 0.f};
    f32x4 acc1 = {0.f, 0.f, 0.f, 0.f};
    f32x4 acc2 = {0.f, 0.f, 0.f, 0.f};
    f32x4 acc3 = {0.f, 0.f, 0.f, 0.f};
#pragma unroll
    for (int ks = 0; ks < 8; ks++) {
        int c16a = ks * 8 + lq * 2;          // first 16B chunk of this A-frag
        f32x4 va = *(const f32x4*)&xsf[r * 256 + (((c16a + 0) ^ (r & 7)) << 2)];
        f32x4 vb = *(const f32x4*)&xsf[r * 256 + (((c16a + 1) ^ (r & 7)) << 2)];
        bf16x8 a;
        a[0] = (short)f2bf(va[0]); a[1] = (short)f2bf(va[1]);
        a[2] = (short)f2bf(va[2]); a[3] = (short)f2bf(va[3]);
        a[4] = (short)f2bf(vb[0]); a[5] = (short)f2bf(vb[1]);
        a[6] = (short)f2bf(vb[2]); a[7] = (short)f2bf(vb[3]);
        bf16x8 b0 = *(const bf16x8*)&Winb[((jb + 0) * 16 + lrow) * 256 + ks * 32 + lq * 8];
        bf16x8 b1 = *(const bf16x8*)&Winb[((jb + 2) * 16 + lrow) * 256 + ks * 32 + lq * 8];
        bf16x8 b2 = *(const bf16x8*)&Winb[((jb + 4) * 16 + lrow) * 256 + ks * 32 + lq * 8];
        bf16x8 b3 = *(const bf16x8*)&Winb[((jb + 6) * 16 + lrow) * 256 + ks * 32 + lq * 8];
        acc0 = __builtin_amdgcn_mfma_f32_16x16x32_bf16(a, b0, acc0, 0, 0, 0);
        acc1 = __builtin_amdgcn_mfma_f32_16x16x32_bf16(a, b1, acc1, 0, 0, 0);
        acc2 = __builtin_amdgcn_mfma_f32_16x16x32_bf16(a, b2, acc2, 0, 0, 0);
        acc3 = __builtin_amdgcn_mfma_f32_16x16x32_bf16(a, b3, acc3, 0, 0, 0);
    }

    // ---- epilogue: stage bf16 results in LDS (aliases dead x-tile), coalesced stores ----
    __syncthreads();
    short* sb = (short*)xsf;
#pragma unroll
    for (int q = 0; q < 4; q++) {
        f32x4 accq = (q == 0) ? acc0 : (q == 1) ? acc1 : (q == 2) ? acc2 : acc3;
        int j0 = (jb + 2 * q) * 16;
        float bj = bin[j0 + lrow];
#pragma unroll
        for (int rr = 0; rr < 4; rr++) {
            int rowm = mt + lq * 4 + rr;         // C/D: col=lane&15, row=quad*4+reg
            float h = fmaxf(accq[rr] + bj, 0.f);
            sb[rowm * SBST + j0 + lrow] = (short)f2bf(h);
            sb[GOFF + rowm * SBST + j0 + lrow] = (short)f2bf(s_dv[rowm] * h);
        }
    }
    __syncthreads();
    for (int idx = t; idx < NB * 16; idx += 256) {
        int rowm = idx >> 4;
        int c = (idx & 15) * 8;
        int dst = base + rowm;
        if (dst < N) {
            *(bf16x8*)&h0b[(size_t)dst * HID + c] = *(const bf16x8*)&sb[rowm * SBST + c];
            *(bf16x8*)&g[(size_t)dst * HID + c]   = *(const bf16x8*)&sb[GOFF + rowm * SBST + c];
        }
    }
}

// ---------- fused layer (g-space): T = g[dst] + sum_nbr g[src];
// s = 0.9*dinv[dst]*T + 0.1*h0 ; h_next = relu(s @ W') ; g_out = bf16(dinv*h_next)
// Gather = r7 structure (LDS indices, 16 uint32 gathers/round) with scalar
// clamp-and-correct tail (no per-slot guards). Last layer (Wout != null):
// fused output dot, no g_out write.
__global__ __launch_bounds__(256, 4) void layer_k(const ushort_t* __restrict__ g_in,
                                                  ushort_t* __restrict__ g_out,
                                                  const ushort_t* __restrict__ h0b,
                                                  const float* __restrict__ dinv,
                                                  const int* __restrict__ row_ptr,
                                                  const int* __restrict__ srcS,
                                                  const short* __restrict__ Wtb,
                                                  int N,
                                                  const float* __restrict__ Wout,
                                                  const float* __restrict__ bout,
                                                  float* __restrict__ outp) {
    __shared__ int   s_idx[CAP];        // 4 KB — block's staged edge list
    __shared__ int   s_rp[NB + 1];
    __shared__ short s_bf[NB * SBST];   // 8.7 KB — bf16 s for MFMA A-frags, then staging
    __shared__ float s_dv[NB];
    int t = threadIdx.x;
    int lane = t & 63;
    int wv = t >> 6;
    int base = blockIdx.x * NB;

    if (t < NB + 1) s_rp[t] = row_ptr[min(base + t, N)];
    if (t < NB) s_dv[t] = (base + t < N) ? dinv[base + t] : 1.f;
    int blk_beg = row_ptr[base];
    int blk_end = row_ptr[min(base + NB, N)];
    int nE = blk_end - blk_beg;
    int nL = nE < CAP ? nE : CAP;
    for (int i = t; i < nL; i += 256) s_idx[i] = srcS[blk_beg + i];   // coalesced
    __syncthreads();

    const char* gbp = (const char*)g_in;
    uint32 lb = (uint32)(lane << 2);
    for (int m = wv; m < NB; m += 4) {
        int dst = base + m;
        if (dst >= N) {
            *(uint32*)&s_bf[m * SBST + lane * 2] = 0;
            continue;
        }
        float dv = s_dv[m];
        uint32 gd = ((const uint32*)(g_in + (size_t)dst * HID))[lane];   // self
        uint32 hu = ((const uint32*)(h0b + (size_t)dst * HID))[lane];    // h0
        float ax = bf_lo(gd), ay = bf_hi(gd);
        int beg = s_rp[m], end = s_rp[m + 1];
        int deg = end - beg;
        if (deg > 0) {
            int nR = (deg + 15) >> 4;
            bool fastp = (end - blk_beg) <= nL;      // ~always true
            if (fastp) {
                int eb0 = beg - blk_beg;
                int lastI = eb0 + deg - 1;
                for (int r = 0; r < nR; r++) {
                    int e = eb0 + (r << 4);          // slots clamped (scalar min)
                    int i0  = s_idx[min(e + 0,  lastI)];
                    int i1  = s_idx[min(e + 1,  lastI)];
                    int i2  = s_idx[min(e + 2,  lastI)];
                    int i3  = s_idx[min(e + 3,  lastI)];
                    int i4  = s_idx[min(e + 4,  lastI)];
                    int i5  = s_idx[min(e + 5,  lastI)];
                    int i6  = s_idx[min(e + 6,  lastI)];
                    int i7  = s_idx[min(e + 7,  lastI)];
                    int i8  = s_idx[min(e + 8,  lastI)];
                    int i9  = s_idx[min(e + 9,  lastI)];
                    int i10 = s_idx[min(e + 10, lastI)];
                    int i11 = s_idx[min(e + 11, lastI)];
                    int i12 = s_idx[min(e + 12, lastI)];
                    int i13 = s_idx[min(e + 13, lastI)];
                    int i14 = s_idx[min(e + 14, lastI)];
                    int i15 = s_idx[min(e + 15, lastI)];
                    uint32 g0  = *(const uint32*)(gbp + (((uint32)i0  << 8) | lb));
                    uint32 g1  = *(const uint32*)(gbp + (((uint32)i1  << 8) | lb));
                    uint32 g2  = *(const uint32*)(gbp + (((uint32)i2  << 8) | lb));
                    uint32 g3  = *(const uint32*)(gbp + (((uint32)i3  << 8) | lb));
                    uint32 g4  = *(const uint32*)(gbp + (((uint32)i4  << 8) | lb));
                    uint32 g5  = *(const uint32*)(gbp + (((uint32)i5  << 8) | lb));
                    uint32 g6  = *(const uint32*)(gbp + (((uint32)i6  << 8) | lb));
                    uint32 g7  = *(const uint32*)(gbp + (((uint32)i7  << 8) | lb));
                    uint32 g8  = *(const uint32*)(gbp + (((uint32)i8  << 8) | lb));
                    uint32 g9  = *(const uint32*)(gbp + (((uint32)i9  << 8) | lb));
                    uint32 g10 = *(const uint32*)(gbp + (((uint32)i10 << 8) | lb));
                    uint32 g11 = *(const uint32*)(gbp + (((uint32)i11 << 8) | lb));
                    uint32 g12 = *(const uint32*)(gbp + (((uint32)i12 << 8) | lb));
                    uint32 g13 = *(const uint32*)(gbp + (((uint32)i13 << 8) | lb));
                    uint32 g14 = *(const uint32*)(gbp + (((uint32)i14 << 8) | lb));
                    uint32 g15 = *(const uint32*)(gbp + (((uint32)i15 << 8) | lb));
                    ax += bf_lo(g0);  ay += bf_hi(g0);
                    ax += bf_lo(g1);  ay += bf_hi(g1);
                    ax += bf_lo(g2);  ay += bf_hi(g2);
                    ax += bf_lo(g3);  ay += bf_hi(g3);
                    ax += bf_lo(g4);  ay += bf_hi(g4);
                    ax += bf_lo(g5);  ay += bf_hi(g5);
                    ax += bf_lo(g6);  ay += bf_hi(g6);
                    ax += bf_lo(g7);  ay += bf_hi(g7);
                    ax += bf_lo(g8);  ay += bf_hi(g8);
                    ax += bf_lo(g9);  ay += bf_hi(g9);
                    ax += bf_lo(g10); ay += bf_hi(g10);
                    ax += bf_lo(g11); ay += bf_hi(g11);
                    ax += bf_lo(g12); ay += bf_hi(g12);
                    ax += bf_lo(g13); ay += bf_hi(g13);
                    ax += bf_lo(g14); ay += bf_hi(g14);
                    ax += bf_lo(g15); ay += bf_hi(g15);
                }
                if (deg & 15) {      // subtract duplicated last-edge contributions
                    int cnt = (nR << 4) - deg;
                    uint32 gl = *(const uint32*)(gbp + (((uint32)s_idx[lastI] << 8) | lb));
                    float fc = (float)cnt;
                    ax -= fc * bf_lo(gl);
                    ay -= fc * bf_hi(gl);
                }
            } else {
                // fallback (statistically unreachable): indices from global srcS
                int lastA = end - 1;
                for (int r = 0; r < nR; r++) {
                    int e = beg + (r << 4);
#pragma unroll
                    for (int k = 0; k < 16; k++) {
                        int sn = srcS[min(e + k, lastA)];
                        uint32 gg = *(const uint32*)(gbp + (((uint32)sn << 8) | lb));
                        ax += bf_lo(gg); ay += bf_hi(gg);
                    }
                }
                if (deg & 15) {
                    int cnt = (nR << 4) - deg;
                    uint32 gl = *(const uint32*)(gbp + (((uint32)srcS[lastA] << 8) | lb));
                    float fc = (float)cnt;
                    ax -= fc * bf_lo(gl);
                    ay -= fc * bf_hi(gl);
                }
            }
        }
        float sc = 0.9f * dv;
        float sx = sc * ax + 0.1f * bf_lo(hu);
        float sy = sc * ay + 0.1f * bf_hi(hu);
        uint32 pk = ((uint32)f2bf(sy) << 16) | (uint32)f2bf(sx);
        *(uint32*)&s_bf[m * SBST + lane * 2] = pk;
    }
    __syncthreads();

    // ---- Phase B: y = s @ W' via MFMA 16x16x32 bf16 (residual folded into W') ----
    int mt = (wv & 1) * 16;
    int jb = wv >> 1;
    int lrow = lane & 15;
    int lq = lane >> 4;
    f32x4 acc0 = {0.f, 0.f, 0.f, 0.f};
    f32x4 acc1 = {0.f, 0.f, 0.f, 0.f};
    f32x4 acc2 = {0.f, 0.f, 0.f, 0.f};
    f32x4 acc3 = {0.f, 0.f, 0.f, 0.f};
#pragma unroll
    for (int ks = 0; ks < 4; ks++) {
        bf16x8 a = *(const bf16x8*)&s_bf[(mt + lrow) * SBST + ks * 32 + lq * 8];
        bf16x8 b0 = *(const bf16x8*)&Wtb[((jb + 0) * 16 + lrow) * 128 + ks * 32 + lq * 8];
        bf16x8 b1 = *(const bf16x8*)&Wtb[((jb + 2) * 16 + lrow) * 128 + ks * 32 + lq * 8];
        bf16x8 b2 = *(const bf16x8*)&Wtb[((jb + 4) * 16 + lrow) * 128 + ks * 32 + lq * 8];
        bf16x8 b3 = *(const bf16x8*)&Wtb[((jb + 6) * 16 + lrow) * 128 + ks * 32 + lq * 8];
        acc0 = __builtin_amdgcn_mfma_f32_16x16x32_bf16(a, b0, acc0, 0, 0, 0);
        acc1 = __builtin_amdgcn_mfma_f32_16x16x32_bf16(a, b1, acc1, 0, 0, 0);
        acc2 = __builtin_amdgcn_mfma_f32_16x16x32_bf16(a, b2, acc2, 0, 0, 0);
        acc3 = __builtin_amdgcn_mfma_f32_16x16x32_bf16(a, b3, acc3, 0, 0, 0);
    }

    __syncthreads();   // all A-frag reads done before s_bf overwrite
    if (Wout == nullptr) {
        // ---- normal epilogue: g_out = bf16(dinv * relu(acc)), coalesced stores ----
#pragma unroll
        for (int q = 0; q < 4; q++) {
            f32x4 accq = (q == 0) ? acc0 : (q == 1) ? acc1 : (q == 2) ? acc2 : acc3;
            int j0 = (jb + 2 * q) * 16;
#pragma unroll
            for (int r = 0; r < 4; r++) {
                int rowm = mt + lq * 4 + r;      // C/D: col=lane&15, row=quad*4+reg
                float h = fmaxf(accq[r], 0.f);
                s_bf[rowm * SBST + j0 + lrow] = (short)f2bf(s_dv[rowm] * h);
            }
        }
        __syncthreads();
        for (int idx = t; idx < NB * 16; idx += 256) {
            int rowm = idx >> 4;
            int cc = (idx & 15) * 8;
            int dst = base + rowm;
            if (dst < N)
                *(bf16x8*)&g_out[(size_t)dst * HID + cc] = *(const bf16x8*)&s_bf[rowm * SBST + cc];
        }
    } else {
        // ---- fused final output: out[n] = relu(h) . Wout + bout (no g_out write) ----
#pragma unroll
        for (int q = 0; q < 4; q++) {
            f32x4 accq = (q == 0) ? acc0 : (q == 1) ? acc1 : (q == 2) ? acc2 : acc3;
            int j0 = (jb + 2 * q) * 16;
#pragma unroll
            for (int r = 0; r < 4; r++) {
                int rowm = mt + lq * 4 + r;
                s_bf[rowm * SBST + j0 + lrow] = (short)f2bf(fmaxf(accq[r], 0.f));
            }
        }
        __syncthreads();
        float w0 = Wout[lane * 2];
        float w1 = Wout[lane * 2 + 1];
        float bo = bout[0];
        for (int rr = 0; rr < 8; rr++) {
            int rowm = wv * 8 + rr;              // wave wv owns rows wv*8..wv*8+7
            uint32 u = *(const uint32*)&s_bf[rowm * SBST + lane * 2];
            float v = bf_lo(u) * w0 + bf_hi(u) * w1;
#pragma unroll
            for (int off = 32; off > 0; off >>= 1) v += __shfl_down(v, off, 64);
            if (lane == 0 && base + rowm < N) outp[base + rowm] = v + bo;
        }
    }
}

extern "C" void kernel_launch(void* const* d_in, const int* in_sizes, int n_in,
                              void* d_out, int out_size, void* d_ws, size_t ws_size,
                              hipStream_t stream) {
    const float* x    = (const float*)d_in[0];
    const int*   ei   = (const int*)d_in[1];
    const float* Win  = (const float*)d_in[2];
    const float* bin  = (const float*)d_in[3];
    const float* convs= (const float*)d_in[4];
    const float* Wout = (const float*)d_in[5];
    const float* bout = (const float*)d_in[6];

    int N = in_sizes[0] / 256;
    int E = in_sizes[1] / 2;
    const int* row = ei;       // sources
    const int* col = ei + E;   // destinations

    char* ws = (char*)d_ws;
    size_t off = 0;
    auto alloc = [&](size_t bytes) -> char* {
        char* p = ws + off;
        off = (off + bytes + 255) & ~(size_t)255;
        return p;
    };
    int NCO = (N + (1 << CSH) - 1) >> CSH;      // 512-node coarse buckets (196; <=512 req'd)
    int*      row_ptr   = (int*)alloc((size_t)(N + 1) * 4);
    int*      bcnt      = (int*)alloc((size_t)NCO * 4);
    int*      bstart    = (int*)alloc((size_t)(NCO + 1) * 4);
    int*      ccursor   = (int*)alloc((size_t)NCO * 4);
    float*    dinv      = (float*)alloc((size_t)N * 4);
    int*      srcS      = (int*)alloc((size_t)E * 4);
    short*    Wt        = (short*)alloc((size_t)8 * 128 * 128 * 2);
    short*    Winb      = (short*)alloc((size_t)256 * 128 * 2);
    ushort_t* h0b       = (ushort_t*)alloc((size_t)N * HID * 2);
    ushort_t* gA        = (ushort_t*)alloc((size_t)N * HID * 2);
    ushort_t* gB        = (ushort_t*)alloc((size_t)N * HID * 2);
    // ebuf (E int2 = 12.8 MB) aliases gB: consumed in cfinal2 before h0_k; gB
    // first written by layer 0. Stream-ordered, so no overlap in lifetime.
    int2*     ebuf      = (int2*)gB;

    int mb = (E + MCH - 1) / MCH;

    hipMemsetAsync(bcnt, 0, (size_t)NCO * 4, stream);
    bcount_k<<<mb, 256, 0, stream>>>(col, bcnt, E, NCO);
    bscan_k<<<1, 512, 0, stream>>>(bcnt, bstart, ccursor, NCO, E);
    multisplit_k<<<mb, 256, 0, stream>>>(row, col, ccursor, ebuf, E, NCO);
    cfinal2_k<<<NCO, 256, 0, stream>>>(ebuf, bstart, row_ptr, dinv, srcS, N, E);
    wprep_k<<<512, 256, 0, stream>>>(convs, Wt);
    winprep_k<<<128, 256, 0, stream>>>(Win, Winb);

    int gb = (N + NB - 1) / NB;
    h0_k<<<gb, 256, 0, stream>>>(x, Winb, bin, dinv, h0b, gA, N);

    ushort_t* gin = gA;
    ushort_t* gout = gB;
    for (int i = 0; i < 8; i++) {
        bool last = (i == 7);
        layer_k<<<gb, 256, 0, stream>>>(gin, gout, h0b, dinv, row_ptr, srcS,
                                        Wt + (size_t)i * 128 * 128, N,
                                        last ? Wout : nullptr, bout, (float*)d_out);
        ushort_t* tp = gin; gin = gout; gout = tp;
    }
}

// Round 13
// 889.230 us; speedup vs baseline: 2.4270x; 1.0305x over previous
//
#include <hip/hip_runtime.h>
#include <math.h>

#define HID 128
#define NB 32     // nodes per block
#define SBST 136  // padded bf16 row stride for s_bf (16B-aligned, 2-way banks)
#define CSH 9     // coarse bucket = dst >> CSH (512 nodes/bucket); NCO must be <=512
#define MCH 8192  // edges per multisplit block
#define GOFF (32 * SBST)   // h0_k epilogue: g-staging offset inside LDS
#define CAP 1024  // per-block staged edge capacity (mean 512, +22 sigma safe)

typedef unsigned int uint32;
typedef unsigned short ushort_t;
typedef __attribute__((ext_vector_type(8))) short bf16x8;
typedef __attribute__((ext_vector_type(4))) float f32x4;

__device__ __forceinline__ unsigned short f2bf(float f) {
    unsigned u = __float_as_uint(f);
    u += 0x7FFF + ((u >> 16) & 1);          // round-to-nearest-even
    return (unsigned short)(u >> 16);
}
__device__ __forceinline__ float bf_lo(uint32 u) { return __uint_as_float(u << 16); }
__device__ __forceinline__ float bf_hi(uint32 u) { return __uint_as_float(u & 0xFFFF0000u); }

// ---------- CSR build (bucket-level only; per-node work moves to cfinal2's LDS) ----------
// LDS-aggregated bucket count (r11 lesson: atomic cost scales with OPS-PER-ADDRESS).
__global__ __launch_bounds__(256) void bcount_k(const int* __restrict__ col,
                                                int* __restrict__ bcnt, int E, int NCO) {
    __shared__ int lcnt[512];
    int t = threadIdx.x;
    lcnt[t] = 0;
    lcnt[t + 256] = 0;
    __syncthreads();
    int e0 = blockIdx.x * MCH;
    for (int i = t; i < MCH; i += 256) {
        int e = e0 + i;
        if (e < E) atomicAdd(&lcnt[col[e] >> CSH], 1);
    }
    __syncthreads();
    if (t < NCO && lcnt[t] > 0) atomicAdd(&bcnt[t], lcnt[t]);
}

// one-block exclusive scan over NCO (<=512) bucket counts
__global__ void bscan_k(const int* __restrict__ bcnt, int* __restrict__ bstart,
                        int* __restrict__ ccursor, int nco, int E) {
    __shared__ int tmp[512];
    int t = threadIdx.x;
    int v = (t < nco) ? bcnt[t] : 0;
    tmp[t] = v;
    __syncthreads();
    for (int off = 1; off < 512; off <<= 1) {
        int x = (t >= off) ? tmp[t - off] : 0;
        __syncthreads();
        tmp[t] += x;
        __syncthreads();
    }
    if (t < nco) {
        bstart[t] = tmp[t] - v;
        ccursor[t] = tmp[t] - v;
    }
    if (t == 0) bstart[nco] = E;
}

// ---- scatter pass 1: block-aggregated multisplit into coarse buckets.
__global__ __launch_bounds__(256) void multisplit_k(const int* __restrict__ row,
                                                    const int* __restrict__ col,
                                                    int* __restrict__ ccursor,
                                                    int2* __restrict__ ebuf,
                                                    int E, int NCO) {
    __shared__ int lcnt[256];
    __shared__ int gbase[256];
    __shared__ int lpos[256];
    int t = threadIdx.x;
    int e0 = blockIdx.x * MCH;
    lcnt[t] = 0;
    lpos[t] = 0;
    __syncthreads();
    for (int i = t; i < MCH; i += 256) {
        int e = e0 + i;
        if (e < E) atomicAdd(&lcnt[col[e] >> CSH], 1);
    }
    __syncthreads();
    if (t < NCO && lcnt[t] > 0) gbase[t] = atomicAdd(&ccursor[t], lcnt[t]);
    __syncthreads();
    for (int i = t; i < MCH; i += 256) {
        int e = e0 + i;
        if (e < E) {
            int c = col[e];
            int b = c >> CSH;
            int p = atomicAdd(&lpos[b], 1);
            ebuf[gbase[b] + p] = make_int2(row[e], c);
        }
    }
}

// ---- pass 2: per bucket, derive per-node degree/row_ptr/dinv/cursor in LDS,
// then scatter to final CSR position.
__global__ void cfinal2_k(const int2* __restrict__ ebuf, const int* __restrict__ bstart,
                          int* __restrict__ row_ptr, float* __restrict__ dinv,
                          int* __restrict__ srcS, int N, int E) {
    __shared__ int cnt[512];
    __shared__ int tmp[256];
    __shared__ int curs[512];
    int t = threadIdx.x;
    int b = blockIdx.x;
    int n0 = b << CSH;
    int beg = bstart[b];
    int end = bstart[b + 1];
    cnt[t] = 0;
    cnt[t + 256] = 0;
    __syncthreads();
    for (int i = beg + t; i < end; i += 256)
        atomicAdd(&cnt[ebuf[i].y & 511], 1);
    __syncthreads();
    int c0 = cnt[2 * t], c1 = cnt[2 * t + 1];
    int psum = c0 + c1;
    tmp[t] = psum;
    __syncthreads();
    for (int off = 1; off < 256; off <<= 1) {
        int x = (t >= off) ? tmp[t - off] : 0;
        __syncthreads();
        tmp[t] += x;
        __syncthreads();
    }
    int exc0 = tmp[t] - psum;
    int exc1 = exc0 + c0;
    int na = n0 + 2 * t, nb_ = n0 + 2 * t + 1;
    if (na < N) { row_ptr[na] = beg + exc0; dinv[na] = rsqrtf((float)c0 + 1.f); }
    if (nb_ < N) { row_ptr[nb_] = beg + exc1; dinv[nb_] = rsqrtf((float)c1 + 1.f); }
    curs[2 * t] = beg + exc0;
    curs[2 * t + 1] = beg + exc1;
    if (b == 0 && t == 0) row_ptr[N] = E;
    __syncthreads();
    for (int i = beg + t; i < end; i += 256) {
        int2 p = ebuf[i];
        int pos = atomicAdd(&curs[p.y & 511], 1);
        srcS[pos] = p.x;
    }
}

// ---------- Wt[l][n][k] = bf16( beta_l*convs[l][k][n] + (k==n)*(1-beta_l) ) ----------
__global__ void wprep_k(const float* __restrict__ convs, short* __restrict__ Wt) {
    int idx = blockIdx.x * 256 + threadIdx.x;
    if (idx >= 8 * 128 * 128) return;
    int l = idx >> 14;
    int r = idx & 16383;
    int k = r >> 7;
    int n = r & 127;                     // n fastest -> coalesced read
    float beta = logf(0.5f / (float)(l + 1) + 1.0f);
    float v = beta * convs[idx] + ((k == n) ? (1.0f - beta) : 0.0f);
    Wt[(l << 14) + (n << 7) + k] = (short)f2bf(v);
}

// Winb[n][k] = bf16(Win[k][n]), n in [0,128), k in [0,256)
__global__ void winprep_k(const float* __restrict__ Win, short* __restrict__ Winb) {
    int idx = blockIdx.x * 256 + threadIdx.x;
    if (idx >= 256 * 128) return;
    int k = idx >> 7;
    int n = idx & 127;
    Winb[n * 256 + k] = (short)f2bf(Win[idx]);
}

// ---------- h0 via MFMA: h0 = relu(x @ W_in + b_in); h0b = bf16(h0), g = bf16(dinv*h0) ----------
// Staging: global_load_lds width=16, fp32 x, XOR-swizzled 16B chunks (rule #21).
__global__ __launch_bounds__(256) void h0_k(const float* __restrict__ x,
                                            const short* __restrict__ Winb,
                                            const float* __restrict__ bin,
                                            const float* __restrict__ dinv,
                                            ushort_t* __restrict__ h0b,
                                            ushort_t* __restrict__ g,
                                            int N) {
    __shared__ float xsf[NB * 256];          // 32 KB fp32 x-tile
    __shared__ float s_dv[NB];
    int t = threadIdx.x;
    int lane = t & 63, wv = t >> 6;
    int base = blockIdx.x * NB;

    if (t < NB) s_dv[t] = (base + t < N) ? dinv[base + t] : 1.f;

    if (base + NB <= N) {
        const float* xblk = x + (size_t)base * 256;
#pragma unroll
        for (int it = 0; it < 8; it++) {
            int m = wv * 8 + it;
            const float* src = xblk + (size_t)m * 256 + ((lane ^ (m & 7)) << 2);
            __builtin_amdgcn_global_load_lds(
                (const __attribute__((address_space(1))) unsigned int*)src,
                (__attribute__((address_space(3))) unsigned int*)&xsf[m * 256],
                16, 0, 0);
        }
    } else {
        for (int idx = t; idx < NB * 64; idx += 256) {
            int m = idx >> 6;
            int c16 = idx & 63;
            int nn = base + m;
            float4 v = make_float4(0.f, 0.f, 0.f, 0.f);
            if (nn < N) v = *(const float4*)&x[(size_t)nn * 256 + c16 * 4];
            *(float4*)&xsf[m * 256 + ((c16 ^ (m & 7)) << 2)] = v;
        }
    }
    __syncthreads();   // drains vmcnt (gload_lds) before any LDS read

    int mt = (wv & 1) * 16;
    int jb = wv >> 1;
    int lrow = lane & 15;
    int lq = lane >> 4;
    int r = mt + lrow;
    f32x4 acc0 = {0.f, 0.f, 0.f, 0.f};
    f32x4 acc1 = {0.f, 0.f, 0.f, 0.f};
    f32x4 acc2 = {0.f, 0.f, 0.f, 0.f};
    f32x4 acc3 = {0.f, 0.f, 0.f, 0.f};
#pragma unroll
    for (int ks = 0; ks < 8; ks++) {
        int c16a = ks * 8 + lq * 2;          // first 16B chunk of this A-frag
        f32x4 va = *(const f32x4*)&xsf[r * 256 + (((c16a + 0) ^ (r & 7)) << 2)];
        f32x4 vb = *(const f32x4*)&xsf[r * 256 + (((c16a + 1) ^ (r & 7)) << 2)];
        bf16x8 a;
        a[0] = (short)f2bf(va[0]); a[1] = (short)f2bf(va[1]);
        a[2] = (short)f2bf(va[2]); a[3] = (short)f2bf(va[3]);
        a[4] = (short)f2bf(vb[0]); a[5] = (short)f2bf(vb[1]);
        a[6] = (short)f2bf(vb[2]); a[7] = (short)f2bf(vb[3]);
        bf16x8 b0 = *(const bf16x8*)&Winb[((jb + 0) * 16 + lrow) * 256 + ks * 32 + lq * 8];
        bf16x8 b1 = *(const bf16x8*)&Winb[((jb + 2) * 16 + lrow) * 256 + ks * 32 + lq * 8];
        bf16x8 b2 = *(const bf16x8*)&Winb[((jb + 4) * 16 + lrow) * 256 + ks * 32 + lq * 8];
        bf16x8 b3 = *(const bf16x8*)&Winb[((jb + 6) * 16 + lrow) * 256 + ks * 32 + lq * 8];
        acc0 = __builtin_amdgcn_mfma_f32_16x16x32_bf16(a, b0, acc0, 0, 0, 0);
        acc1 = __builtin_amdgcn_mfma_f32_16x16x32_bf16(a, b1, acc1, 0, 0, 0);
        acc2 = __builtin_amdgcn_mfma_f32_16x16x32_bf16(a, b2, acc2, 0, 0, 0);
        acc3 = __builtin_amdgcn_mfma_f32_16x16x32_bf16(a, b3, acc3, 0, 0, 0);
    }

    // ---- epilogue: stage bf16 results in LDS (aliases dead x-tile), coalesced stores ----
    __syncthreads();
    short* sb = (short*)xsf;
#pragma unroll
    for (int q = 0; q < 4; q++) {
        f32x4 accq = (q == 0) ? acc0 : (q == 1) ? acc1 : (q == 2) ? acc2 : acc3;
        int j0 = (jb + 2 * q) * 16;
        float bj = bin[j0 + lrow];
#pragma unroll
        for (int rr = 0; rr < 4; rr++) {
            int rowm = mt + lq * 4 + rr;         // C/D: col=lane&15, row=quad*4+reg
            float h = fmaxf(accq[rr] + bj, 0.f);
            sb[rowm * SBST + j0 + lrow] = (short)f2bf(h);
            sb[GOFF + rowm * SBST + j0 + lrow] = (short)f2bf(s_dv[rowm] * h);
        }
    }
    __syncthreads();
    for (int idx = t; idx < NB * 16; idx += 256) {
        int rowm = idx >> 4;
        int c = (idx & 15) * 8;
        int dst = base + rowm;
        if (dst < N) {
            *(bf16x8*)&h0b[(size_t)dst * HID + c] = *(const bf16x8*)&sb[rowm * SBST + c];
            *(bf16x8*)&g[(size_t)dst * HID + c]   = *(const bf16x8*)&sb[GOFF + rowm * SBST + c];
        }
    }
}

// ---------- fused layer (g-space): T = g[dst] + sum_nbr g[src];
// s = 0.9*dinv[dst]*T + 0.1*h0 ; h_next = relu(s @ W') ; g_out = bf16(dinv*h_next)
// Gather: nfull RAW rounds (no clamp on the load-issue path — r12's all-round
// min() cost ~20% achieved BW) + at most ONE clamped round with unconditional
// adds + single-load correction. Last layer (Wout != null): fused output dot.
__global__ __launch_bounds__(256, 4) void layer_k(const ushort_t* __restrict__ g_in,
                                                  ushort_t* __restrict__ g_out,
                                                  const ushort_t* __restrict__ h0b,
                                                  const float* __restrict__ dinv,
                                                  const int* __restrict__ row_ptr,
                                                  const int* __restrict__ srcS,
                                                  const short* __restrict__ Wtb,
                                                  int N,
                                                  const float* __restrict__ Wout,
                                                  const float* __restrict__ bout,
                                                  float* __restrict__ outp) {
    __shared__ int   s_idx[CAP];        // 4 KB — block's staged edge list
    __shared__ int   s_rp[NB + 1];
    __shared__ short s_bf[NB * SBST];   // 8.7 KB — bf16 s for MFMA A-frags, then staging
    __shared__ float s_dv[NB];
    int t = threadIdx.x;
    int lane = t & 63;
    int wv = t >> 6;
    int base = blockIdx.x * NB;

    if (t < NB + 1) s_rp[t] = row_ptr[min(base + t, N)];
    if (t < NB) s_dv[t] = (base + t < N) ? dinv[base + t] : 1.f;
    int blk_beg = row_ptr[base];
    int blk_end = row_ptr[min(base + NB, N)];
    int nE = blk_end - blk_beg;
    int nL = nE < CAP ? nE : CAP;
    for (int i = t; i < nL; i += 256) s_idx[i] = srcS[blk_beg + i];   // coalesced
    __syncthreads();

    const char* gbp = (const char*)g_in;
    uint32 lb = (uint32)(lane << 2);
    for (int m = wv; m < NB; m += 4) {
        int dst = base + m;
        if (dst >= N) {
            *(uint32*)&s_bf[m * SBST + lane * 2] = 0;
            continue;
        }
        float dv = s_dv[m];
        uint32 gd = ((const uint32*)(g_in + (size_t)dst * HID))[lane];   // self
        uint32 hu = ((const uint32*)(h0b + (size_t)dst * HID))[lane];    // h0
        float ax = bf_lo(gd), ay = bf_hi(gd);
        int beg = s_rp[m], end = s_rp[m + 1];
        int deg = end - beg;
        if (deg > 0) {
            int nfull = deg >> 4;
            bool fastp = (end - blk_beg) <= nL;      // ~always true
            if (fastp) {
                int eb0 = beg - blk_beg;
                int e = eb0;
                for (int r = 0; r < nfull; r++, e += 16) {
                    // RAW round: no clamps on the issue path
                    int i0  = s_idx[e + 0];
                    int i1  = s_idx[e + 1];
                    int i2  = s_idx[e + 2];
                    int i3  = s_idx[e + 3];
                    int i4  = s_idx[e + 4];
                    int i5  = s_idx[e + 5];
                    int i6  = s_idx[e + 6];
                    int i7  = s_idx[e + 7];
                    int i8  = s_idx[e + 8];
                    int i9  = s_idx[e + 9];
                    int i10 = s_idx[e + 10];
                    int i11 = s_idx[e + 11];
                    int i12 = s_idx[e + 12];
                    int i13 = s_idx[e + 13];
                    int i14 = s_idx[e + 14];
                    int i15 = s_idx[e + 15];
                    uint32 g0  = *(const uint32*)(gbp + (((uint32)i0  << 8) | lb));
                    uint32 g1  = *(const uint32*)(gbp + (((uint32)i1  << 8) | lb));
                    uint32 g2  = *(const uint32*)(gbp + (((uint32)i2  << 8) | lb));
                    uint32 g3  = *(const uint32*)(gbp + (((uint32)i3  << 8) | lb));
                    uint32 g4  = *(const uint32*)(gbp + (((uint32)i4  << 8) | lb));
                    uint32 g5  = *(const uint32*)(gbp + (((uint32)i5  << 8) | lb));
                    uint32 g6  = *(const uint32*)(gbp + (((uint32)i6  << 8) | lb));
                    uint32 g7  = *(const uint32*)(gbp + (((uint32)i7  << 8) | lb));
                    uint32 g8  = *(const uint32*)(gbp + (((uint32)i8  << 8) | lb));
                    uint32 g9  = *(const uint32*)(gbp + (((uint32)i9  << 8) | lb));
                    uint32 g10 = *(const uint32*)(gbp + (((uint32)i10 << 8) | lb));
                    uint32 g11 = *(const uint32*)(gbp + (((uint32)i11 << 8) | lb));
                    uint32 g12 = *(const uint32*)(gbp + (((uint32)i12 << 8) | lb));
                    uint32 g13 = *(const uint32*)(gbp + (((uint32)i13 << 8) | lb));
                    uint32 g14 = *(const uint32*)(gbp + (((uint32)i14 << 8) | lb));
                    uint32 g15 = *(const uint32*)(gbp + (((uint32)i15 << 8) | lb));
                    ax += bf_lo(g0);  ay += bf_hi(g0);
                    ax += bf_lo(g1);  ay += bf_hi(g1);
                    ax += bf_lo(g2);  ay += bf_hi(g2);
                    ax += bf_lo(g3);  ay += bf_hi(g3);
                    ax += bf_lo(g4);  ay += bf_hi(g4);
                    ax += bf_lo(g5);  ay += bf_hi(g5);
                    ax += bf_lo(g6);  ay += bf_hi(g6);
                    ax += bf_lo(g7);  ay += bf_hi(g7);
                    ax += bf_lo(g8);  ay += bf_hi(g8);
                    ax += bf_lo(g9);  ay += bf_hi(g9);
                    ax += bf_lo(g10); ay += bf_hi(g10);
                    ax += bf_lo(g11); ay += bf_hi(g11);
                    ax += bf_lo(g12); ay += bf_hi(g12);
                    ax += bf_lo(g13); ay += bf_hi(g13);
                    ax += bf_lo(g14); ay += bf_hi(g14);
                    ax += bf_lo(g15); ay += bf_hi(g15);
                }
                int rem = deg & 15;
                if (rem) {       // single clamped round + correction
                    int lastI = eb0 + deg - 1;
                    int i0  = s_idx[min(e + 0,  lastI)];
                    int i1  = s_idx[min(e + 1,  lastI)];
                    int i2  = s_idx[min(e + 2,  lastI)];
                    int i3  = s_idx[min(e + 3,  lastI)];
                    int i4  = s_idx[min(e + 4,  lastI)];
                    int i5  = s_idx[min(e + 5,  lastI)];
                    int i6  = s_idx[min(e + 6,  lastI)];
                    int i7  = s_idx[min(e + 7,  lastI)];
                    int i8  = s_idx[min(e + 8,  lastI)];
                    int i9  = s_idx[min(e + 9,  lastI)];
                    int i10 = s_idx[min(e + 10, lastI)];
                    int i11 = s_idx[min(e + 11, lastI)];
                    int i12 = s_idx[min(e + 12, lastI)];
                    int i13 = s_idx[min(e + 13, lastI)];
                    int i14 = s_idx[min(e + 14, lastI)];
                    int i15 = s_idx[min(e + 15, lastI)];
                    uint32 g0  = *(const uint32*)(gbp + (((uint32)i0  << 8) | lb));
                    uint32 g1  = *(const uint32*)(gbp + (((uint32)i1  << 8) | lb));
                    uint32 g2  = *(const uint32*)(gbp + (((uint32)i2  << 8) | lb));
                    uint32 g3  = *(const uint32*)(gbp + (((uint32)i3  << 8) | lb));
                    uint32 g4  = *(const uint32*)(gbp + (((uint32)i4  << 8) | lb));
                    uint32 g5  = *(const uint32*)(gbp + (((uint32)i5  << 8) | lb));
                    uint32 g6  = *(const uint32*)(gbp + (((uint32)i6  << 8) | lb));
                    uint32 g7  = *(const uint32*)(gbp + (((uint32)i7  << 8) | lb));
                    uint32 g8  = *(const uint32*)(gbp + (((uint32)i8  << 8) | lb));
                    uint32 g9  = *(const uint32*)(gbp + (((uint32)i9  << 8) | lb));
                    uint32 g10 = *(const uint32*)(gbp + (((uint32)i10 << 8) | lb));
                    uint32 g11 = *(const uint32*)(gbp + (((uint32)i11 << 8) | lb));
                    uint32 g12 = *(const uint32*)(gbp + (((uint32)i12 << 8) | lb));
                    uint32 g13 = *(const uint32*)(gbp + (((uint32)i13 << 8) | lb));
                    uint32 g14 = *(const uint32*)(gbp + (((uint32)i14 << 8) | lb));
                    uint32 g15 = *(const uint32*)(gbp + (((uint32)i15 << 8) | lb));
                    ax += bf_lo(g0);  ay += bf_hi(g0);
                    ax += bf_lo(g1);  ay += bf_hi(g1);
                    ax += bf_lo(g2);  ay += bf_hi(g2);
                    ax += bf_lo(g3);  ay += bf_hi(g3);
                    ax += bf_lo(g4);  ay += bf_hi(g4);
                    ax += bf_lo(g5);  ay += bf_hi(g5);
                    ax += bf_lo(g6);  ay += bf_hi(g6);
                    ax += bf_lo(g7);  ay += bf_hi(g7);
                    ax += bf_lo(g8);  ay += bf_hi(g8);
                    ax += bf_lo(g9);  ay += bf_hi(g9);
                    ax += bf_lo(g10); ay += bf_hi(g10);
                    ax += bf_lo(g11); ay += bf_hi(g11);
                    ax += bf_lo(g12); ay += bf_hi(g12);
                    ax += bf_lo(g13); ay += bf_hi(g13);
                    ax += bf_lo(g14); ay += bf_hi(g14);
                    ax += bf_lo(g15); ay += bf_hi(g15);
                    int cnt = 16 - rem;
                    uint32 gl = *(const uint32*)(gbp + (((uint32)s_idx[lastI] << 8) | lb));
                    float fc = (float)cnt;
                    ax -= fc * bf_lo(gl);
                    ay -= fc * bf_hi(gl);
                }
            } else {
                // fallback (statistically unreachable): indices from global srcS
                int lastA = end - 1;
                int nR = (deg + 15) >> 4;
                for (int r = 0; r < nR; r++) {
                    int e = beg + (r << 4);
#pragma unroll
                    for (int k = 0; k < 16; k++) {
                        int sn = srcS[min(e + k, lastA)];
                        uint32 gg = *(const uint32*)(gbp + (((uint32)sn << 8) | lb));
                        ax += bf_lo(gg); ay += bf_hi(gg);
                    }
                }
                if (deg & 15) {
                    int cnt = (nR << 4) - deg;
                    uint32 gl = *(const uint32*)(gbp + (((uint32)srcS[lastA] << 8) | lb));
                    float fc = (float)cnt;
                    ax -= fc * bf_lo(gl);
                    ay -= fc * bf_hi(gl);
                }
            }
        }
        float sc = 0.9f * dv;
        float sx = sc * ax + 0.1f * bf_lo(hu);
        float sy = sc * ay + 0.1f * bf_hi(hu);
        uint32 pk = ((uint32)f2bf(sy) << 16) | (uint32)f2bf(sx);
        *(uint32*)&s_bf[m * SBST + lane * 2] = pk;
    }
    __syncthreads();

    // ---- Phase B: y = s @ W' via MFMA 16x16x32 bf16 (residual folded into W') ----
    int mt = (wv & 1) * 16;
    int jb = wv >> 1;
    int lrow = lane & 15;
    int lq = lane >> 4;
    f32x4 acc0 = {0.f, 0.f, 0.f, 0.f};
    f32x4 acc1 = {0.f, 0.f, 0.f, 0.f};
    f32x4 acc2 = {0.f, 0.f, 0.f, 0.f};
    f32x4 acc3 = {0.f, 0.f, 0.f, 0.f};
#pragma unroll
    for (int ks = 0; ks < 4; ks++) {
        bf16x8 a = *(const bf16x8*)&s_bf[(mt + lrow) * SBST + ks * 32 + lq * 8];
        bf16x8 b0 = *(const bf16x8*)&Wtb[((jb + 0) * 16 + lrow) * 128 + ks * 32 + lq * 8];
        bf16x8 b1 = *(const bf16x8*)&Wtb[((jb + 2) * 16 + lrow) * 128 + ks * 32 + lq * 8];
        bf16x8 b2 = *(const bf16x8*)&Wtb[((jb + 4) * 16 + lrow) * 128 + ks * 32 + lq * 8];
        bf16x8 b3 = *(const bf16x8*)&Wtb[((jb + 6) * 16 + lrow) * 128 + ks * 32 + lq * 8];
        acc0 = __builtin_amdgcn_mfma_f32_16x16x32_bf16(a, b0, acc0, 0, 0, 0);
        acc1 = __builtin_amdgcn_mfma_f32_16x16x32_bf16(a, b1, acc1, 0, 0, 0);
        acc2 = __builtin_amdgcn_mfma_f32_16x16x32_bf16(a, b2, acc2, 0, 0, 0);
        acc3 = __builtin_amdgcn_mfma_f32_16x16x32_bf16(a, b3, acc3, 0, 0, 0);
    }

    __syncthreads();   // all A-frag reads done before s_bf overwrite
    if (Wout == nullptr) {
        // ---- normal epilogue: g_out = bf16(dinv * relu(acc)), coalesced stores ----
#pragma unroll
        for (int q = 0; q < 4; q++) {
            f32x4 accq = (q == 0) ? acc0 : (q == 1) ? acc1 : (q == 2) ? acc2 : acc3;
            int j0 = (jb + 2 * q) * 16;
#pragma unroll
            for (int r = 0; r < 4; r++) {
                int rowm = mt + lq * 4 + r;      // C/D: col=lane&15, row=quad*4+reg
                float h = fmaxf(accq[r], 0.f);
                s_bf[rowm * SBST + j0 + lrow] = (short)f2bf(s_dv[rowm] * h);
            }
        }
        __syncthreads();
        for (int idx = t; idx < NB * 16; idx += 256) {
            int rowm = idx >> 4;
            int cc = (idx & 15) * 8;
            int dst = base + rowm;
            if (dst < N)
                *(bf16x8*)&g_out[(size_t)dst * HID + cc] = *(const bf16x8*)&s_bf[rowm * SBST + cc];
        }
    } else {
        // ---- fused final output: out[n] = relu(h) . Wout + bout (no g_out write) ----
#pragma unroll
        for (int q = 0; q < 4; q++) {
            f32x4 accq = (q == 0) ? acc0 : (q == 1) ? acc1 : (q == 2) ? acc2 : acc3;
            int j0 = (jb + 2 * q) * 16;
#pragma unroll
            for (int r = 0; r < 4; r++) {
                int rowm = mt + lq * 4 + r;
                s_bf[rowm * SBST + j0 + lrow] = (short)f2bf(fmaxf(accq[r], 0.f));
            }
        }
        __syncthreads();
        float w0 = Wout[lane * 2];
        float w1 = Wout[lane * 2 + 1];
        float bo = bout[0];
        for (int rr = 0; rr < 8; rr++) {
            int rowm = wv * 8 + rr;              // wave wv owns rows wv*8..wv*8+7
            uint32 u = *(const uint32*)&s_bf[rowm * SBST + lane * 2];
            float v = bf_lo(u) * w0 + bf_hi(u) * w1;
#pragma unroll
            for (int off = 32; off > 0; off >>= 1) v += __shfl_down(v, off, 64);
            if (lane == 0 && base + rowm < N) outp[base + rowm] = v + bo;
        }
    }
}

extern "C" void kernel_launch(void* const* d_in, const int* in_sizes, int n_in,
                              void* d_out, int out_size, void* d_ws, size_t ws_size,
                              hipStream_t stream) {
    const float* x    = (const float*)d_in[0];
    const int*   ei   = (const int*)d_in[1];
    const float* Win  = (const float*)d_in[2];
    const float* bin  = (const float*)d_in[3];
    const float* convs= (const float*)d_in[4];
    const float* Wout = (const float*)d_in[5];
    const float* bout = (const float*)d_in[6];

    int N = in_sizes[0] / 256;
    int E = in_sizes[1] / 2;
    const int* row = ei;       // sources
    const int* col = ei + E;   // destinations

    char* ws = (char*)d_ws;
    size_t off = 0;
    auto alloc = [&](size_t bytes) -> char* {
        char* p = ws + off;
        off = (off + bytes + 255) & ~(size_t)255;
        return p;
    };
    int NCO = (N + (1 << CSH) - 1) >> CSH;      // 512-node coarse buckets (196; <=512 req'd)
    int*      row_ptr   = (int*)alloc((size_t)(N + 1) * 4);
    int*      bcnt      = (int*)alloc((size_t)NCO * 4);
    int*      bstart    = (int*)alloc((size_t)(NCO + 1) * 4);
    int*      ccursor   = (int*)alloc((size_t)NCO * 4);
    float*    dinv      = (float*)alloc((size_t)N * 4);
    int*      srcS      = (int*)alloc((size_t)E * 4);
    short*    Wt        = (short*)alloc((size_t)8 * 128 * 128 * 2);
    short*    Winb      = (short*)alloc((size_t)256 * 128 * 2);
    ushort_t* h0b       = (ushort_t*)alloc((size_t)N * HID * 2);
    ushort_t* gA        = (ushort_t*)alloc((size_t)N * HID * 2);
    ushort_t* gB        = (ushort_t*)alloc((size_t)N * HID * 2);
    // ebuf (E int2 = 12.8 MB) aliases gB: consumed in cfinal2 before h0_k; gB
    // first written by layer 0. Stream-ordered, so no overlap in lifetime.
    int2*     ebuf      = (int2*)gB;

    int mb = (E + MCH - 1) / MCH;

    hipMemsetAsync(bcnt, 0, (size_t)NCO * 4, stream);
    bcount_k<<<mb, 256, 0, stream>>>(col, bcnt, E, NCO);
    bscan_k<<<1, 512, 0, stream>>>(bcnt, bstart, ccursor, NCO, E);
    multisplit_k<<<mb, 256, 0, stream>>>(row, col, ccursor, ebuf, E, NCO);
    cfinal2_k<<<NCO, 256, 0, stream>>>(ebuf, bstart, row_ptr, dinv, srcS, N, E);
    wprep_k<<<512, 256, 0, stream>>>(convs, Wt);
    winprep_k<<<128, 256, 0, stream>>>(Win, Winb);

    int gb = (N + NB - 1) / NB;
    h0_k<<<gb, 256, 0, stream>>>(x, Winb, bin, dinv, h0b, gA, N);

    ushort_t* gin = gA;
    ushort_t* gout = gB;
    for (int i = 0; i < 8; i++) {
        bool last = (i == 7);
        layer_k<<<gb, 256, 0, stream>>>(gin, gout, h0b, dinv, row_ptr, srcS,
                                        Wt + (size_t)i * 128 * 128, N,
                                        last ? Wout : nullptr, bout, (float*)d_out);
        ushort_t* tp = gin; gin = gout; gout = tp;
    }
}